// Round 6
// baseline (833.143 us; speedup 1.0000x reference)
//
#include <hip/hip_runtime.h>
#include <hip/hip_bf16.h>

// ---------------------------------------------------------------------------
// GCN via agg-commute: agg(XW) == agg(X)W. z = dinv (.) h stored bf16.
// Fused layer: A_i = dinv_i(sum z[src] + z[i]) -> LDS -> MFMA A@W -> +b, relu,
// x dinv -> bf16. Layer3 P = z2@W3 fused into layer-2 epilogue; agg64 fused
// with mean-pool.
// R15: direct CSR build. Totals show ~255us outside the two fused layers --
//   the 5-dispatch bucketed build (3 LDS-atomic passes, 196-block fill) is
//   the prime suspect. Replace with: deg_count (global atomics), scan_all
//   (one 1024-thr block, serial-per-thread scan of 100K degs, also zeros
//   gsum/zrow + writes dinv/cursor), csr_scatter (atomic cursor, one scatter
//   pass -- drops the pairs intermediate entirely). prep_wt merged into
//   prep_x. 11 -> 9 dispatches. fused_layer / agg_pool / finalize unchanged.
// ---------------------------------------------------------------------------

#define THREADS 256

typedef __attribute__((ext_vector_type(8))) short short8;
typedef __attribute__((ext_vector_type(16))) float floatx16;

__device__ __forceinline__ unsigned f2bf(float f) {  // fp32 -> bf16 bits, RNE
    unsigned u = __float_as_uint(f);
    return (u + 0x7fffu + ((u >> 16) & 1u)) >> 16;
}

__device__ __forceinline__ void bf8_acc(uint4 v, float* ac) {
    ac[0] += __uint_as_float(v.x << 16);
    ac[1] += __uint_as_float(v.x & 0xffff0000u);
    ac[2] += __uint_as_float(v.y << 16);
    ac[3] += __uint_as_float(v.y & 0xffff0000u);
    ac[4] += __uint_as_float(v.z << 16);
    ac[5] += __uint_as_float(v.z & 0xffff0000u);
    ac[6] += __uint_as_float(v.w << 16);
    ac[7] += __uint_as_float(v.w & 0xffff0000u);
}

// ---- direct CSR build ------------------------------------------------------

// 4 edges/thread; 1.6M global atomics into N-entry deg[] (L2-resident).
__global__ __launch_bounds__(THREADS) void deg_count(const int* __restrict__ dst,
                                                     int* __restrict__ deg, int E) {
#pragma unroll
    for (int j = 0; j < 4; ++j) {
        int e = blockIdx.x * (THREADS * 4) + j * THREADS + threadIdx.x;
        if (e < E) atomicAdd(&deg[dst[e]], 1);
    }
}

// one block: exclusive scan of deg[0..N) -> row_start/cursor, dinv; zeros
// gsum + zrow. Thread t owns contiguous nodes [t*per, (t+1)*per).
__global__ __launch_bounds__(1024) void scan_all(const int* __restrict__ deg,
                                                 int* __restrict__ row_start,
                                                 int* __restrict__ cursor,
                                                 float* __restrict__ dinv,
                                                 float* __restrict__ gsum,
                                                 float* __restrict__ zrow,
                                                 int N, int E) {
    __shared__ int lds[1024];
    int t = threadIdx.x;
    int per = (N + 1023) >> 10;
    int g0 = t * per;
    int sum = 0;
#pragma unroll 4
    for (int j = 0; j < per; ++j) {
        int g = g0 + j;
        if (g < N) sum += deg[g];
    }
    lds[t] = sum;
    __syncthreads();
    for (int off = 1; off < 1024; off <<= 1) {
        int v = (t >= off) ? lds[t - off] : 0;
        __syncthreads();
        lds[t] += v;
        __syncthreads();
    }
    int run = lds[t] - sum;  // exclusive prefix
#pragma unroll 4
    for (int j = 0; j < per; ++j) {
        int g = g0 + j;
        if (g < N) {
            int d = deg[g];
            row_start[g] = run;
            cursor[g] = run;
            dinv[g] = rsqrtf(1.0f + (float)d);  // deg = 1 + in-degree (self-loop)
            run += d;
        }
    }
    if (t == 0) row_start[N] = E;
    for (int i = t; i < 64 * 64; i += 1024) gsum[i] = 0.0f;
    if (t < 64) zrow[t] = 0.0f;
}

// 4 edges/thread; one scatter pass: esrc[atomicAdd(cursor[dst])] = src.
__global__ __launch_bounds__(THREADS) void csr_scatter(const int* __restrict__ src,
                                                       const int* __restrict__ dst,
                                                       int* __restrict__ cursor,
                                                       int* __restrict__ esrc, int E) {
#pragma unroll
    for (int j = 0; j < 4; ++j) {
        int e = blockIdx.x * (THREADS * 4) + j * THREADS + threadIdx.x;
        if (e < E) {
            int d = dst[e];
            int p = atomicAdd(&cursor[d], 1);
            esrc[p] = src[e];
        }
    }
}

// ---- prep: z1 = bf16(dinv (.) x) AND all three W^T packs (one launch) ------
__device__ __forceinline__ void wt_pack(const float* W, uint4* Wtp, int C, int li) {
    int c = li >> 4, ch = li & 15;
    unsigned r[8];
#pragma unroll
    for (int j = 0; j < 8; ++j) r[j] = f2bf(W[(size_t)(ch * 8 + j) * C + c]);
    uint4 o;
    o.x = r[0] | (r[1] << 16);
    o.y = r[2] | (r[3] << 16);
    o.z = r[4] | (r[5] << 16);
    o.w = r[6] | (r[7] << 16);
    Wtp[li] = o;
}

__global__ __launch_bounds__(THREADS) void prep_all(const float* __restrict__ x,
                                                    const float* __restrict__ dinv,
                                                    uint4* __restrict__ Z,
                                                    const float* __restrict__ W1,
                                                    const float* __restrict__ W2,
                                                    const float* __restrict__ W3,
                                                    uint4* __restrict__ Wt1,
                                                    uint4* __restrict__ Wt2,
                                                    uint4* __restrict__ Wt3, int n) {
    int idx = blockIdx.x * THREADS + threadIdx.x;  // r*16 + chunk
    int nz = n * 16;
    if (idx < nz) {
        int r = idx >> 4, c = idx & 15;
        float dv = dinv[r];
        const float* p = x + (size_t)r * 128 + c * 8;
        float4 a = *(const float4*)p;
        float4 b = *(const float4*)(p + 4);
        uint4 o;
        o.x = f2bf(a.x * dv) | (f2bf(a.y * dv) << 16);
        o.y = f2bf(a.z * dv) | (f2bf(a.w * dv) << 16);
        o.z = f2bf(b.x * dv) | (f2bf(b.y * dv) << 16);
        o.w = f2bf(b.z * dv) | (f2bf(b.w * dv) << 16);
        Z[idx] = o;
    } else {
        int k = idx - nz;
        if (k < 2048) wt_pack(W1, Wt1, 128, k);
        else if (k < 4096) wt_pack(W2, Wt2, 128, k - 2048);
        else if (k < 5120) wt_pack(W3, Wt3, 64, k - 4096);
    }
}

// ---- fused layer: gather -> LDS -> MFMA -> epilogue (+optional P=z2@W3) ----
__global__ __launch_bounds__(THREADS) void fused_layer(const uint4* __restrict__ Z,
                                                       const uint4* __restrict__ Wt,
                                                       const int* __restrict__ row_start,
                                                       const int* __restrict__ esrc,
                                                       const float* __restrict__ dinv,
                                                       const float* __restrict__ bias,
                                                       const uint4* __restrict__ zrow,
                                                       uint4* __restrict__ out,
                                                       const uint4* __restrict__ WtP,
                                                       uint4* __restrict__ outP, int n) {
    __shared__ __align__(16) uint4 ldsX[64 * 16];  // 16KB: A-tile, reused for out-stage
    int row0 = blockIdx.x * 64;
    int maxr = n - row0;
    if (maxr > 64) maxr = 64;
    int tid = threadIdx.x;
    int lane = tid & 15, grp = tid >> 4;
    const uint4* zl = zrow + lane;

    // ---- gather phase: 16 lanes/node, 16 nodes concurrent, 4 rounds ----
    for (int round = 0; round < 4; ++round) {
        int r = round * 16 + grp;
        int node = row0 + r;
        int nd = (node < n) ? node : (n - 1);
        float ac[8] = {0, 0, 0, 0, 0, 0, 0, 0};
        bf8_acc(Z[(size_t)nd * 16 + lane], ac);  // self term z[i]
        float dv = dinv[nd];                     // hoisted: in flight during gather
        int s = row_start[nd], e = row_start[nd + 1];
        int i = s;
        int nmain = (e - s) >> 3;
        if (nmain > 0) {
            int s0 = esrc[i], s1 = esrc[i + 1], s2 = esrc[i + 2], s3 = esrc[i + 3];
            int s4 = esrc[i + 4], s5 = esrc[i + 5], s6 = esrc[i + 6], s7 = esrc[i + 7];
            for (int m = 0; m < nmain; ++m) {
                uint4 v0 = Z[(size_t)s0 * 16 + lane];
                uint4 v1 = Z[(size_t)s1 * 16 + lane];
                uint4 v2 = Z[(size_t)s2 * 16 + lane];
                uint4 v3 = Z[(size_t)s3 * 16 + lane];
                uint4 v4 = Z[(size_t)s4 * 16 + lane];
                uint4 v5 = Z[(size_t)s5 * 16 + lane];
                uint4 v6 = Z[(size_t)s6 * 16 + lane];
                uint4 v7 = Z[(size_t)s7 * 16 + lane];
                int ni = i + 8;
                // prefetch next chunk's esrc (overread <=7 ints: valid ws memory)
                int t0 = esrc[ni], t1 = esrc[ni + 1], t2 = esrc[ni + 2], t3 = esrc[ni + 3];
                int t4 = esrc[ni + 4], t5 = esrc[ni + 5], t6 = esrc[ni + 6], t7 = esrc[ni + 7];
                bf8_acc(v0, ac); bf8_acc(v1, ac); bf8_acc(v2, ac); bf8_acc(v3, ac);
                bf8_acc(v4, ac); bf8_acc(v5, ac); bf8_acc(v6, ac); bf8_acc(v7, ac);
                s0 = t0; s1 = t1; s2 = t2; s3 = t3;
                s4 = t4; s5 = t5; s6 = t6; s7 = t7;
                i = ni;
            }
        }
        if (i < e) {  // masked branchless 8-wide tail (1..7 valid slots)
            const uint4* p0 = (i + 0 < e) ? (Z + ((size_t)esrc[i + 0] * 16 + lane)) : zl;
            const uint4* p1 = (i + 1 < e) ? (Z + ((size_t)esrc[i + 1] * 16 + lane)) : zl;
            const uint4* p2 = (i + 2 < e) ? (Z + ((size_t)esrc[i + 2] * 16 + lane)) : zl;
            const uint4* p3 = (i + 3 < e) ? (Z + ((size_t)esrc[i + 3] * 16 + lane)) : zl;
            const uint4* p4 = (i + 4 < e) ? (Z + ((size_t)esrc[i + 4] * 16 + lane)) : zl;
            const uint4* p5 = (i + 5 < e) ? (Z + ((size_t)esrc[i + 5] * 16 + lane)) : zl;
            const uint4* p6 = (i + 6 < e) ? (Z + ((size_t)esrc[i + 6] * 16 + lane)) : zl;
            const uint4* p7 = (i + 7 < e) ? (Z + ((size_t)esrc[i + 7] * 16 + lane)) : zl;
            uint4 v0 = *p0; uint4 v1 = *p1; uint4 v2 = *p2; uint4 v3 = *p3;
            uint4 v4 = *p4; uint4 v5 = *p5; uint4 v6 = *p6; uint4 v7 = *p7;
            bf8_acc(v0, ac); bf8_acc(v1, ac); bf8_acc(v2, ac); bf8_acc(v3, ac);
            bf8_acc(v4, ac); bf8_acc(v5, ac); bf8_acc(v6, ac); bf8_acc(v7, ac);
        }
        // A_i = dinv_i * (sum z[src] + z[i])
        uint4 o;
        o.x = f2bf(ac[0] * dv) | (f2bf(ac[1] * dv) << 16);
        o.y = f2bf(ac[2] * dv) | (f2bf(ac[3] * dv) << 16);
        o.z = f2bf(ac[4] * dv) | (f2bf(ac[5] * dv) << 16);
        o.w = f2bf(ac[6] * dv) | (f2bf(ac[7] * dv) << 16);
        ldsX[r * 16 + (lane ^ (r & 7))] = o;
    }
    __syncthreads();

    // ---- MFMA phase: D = W^T A^T ; W read from L2-hot global ----
    int l = tid & 63, wv = tid >> 6;
    int l31 = l & 31, half = l >> 5;
    int nt = wv & 1, mt0 = (wv >> 1) * 2;
    floatx16 acc[2];
#pragma unroll
    for (int t = 0; t < 2; ++t)
#pragma unroll
        for (int q = 0; q < 16; ++q) acc[t][q] = 0.0f;
    int xrow = nt * 32 + l31, xsw = xrow & 7;
#pragma unroll
    for (int kt = 0; kt < 8; ++kt) {
        int chunk = kt * 2 + half;
        short8 xf = *(const short8*)&ldsX[xrow * 16 + (chunk ^ xsw)];
#pragma unroll
        for (int t = 0; t < 2; ++t) {
            int c = (mt0 + t) * 32 + l31;
            short8 wf = *(const short8*)&Wt[c * 16 + chunk];
            acc[t] = __builtin_amdgcn_mfma_f32_32x32x16_bf16(wf, xf, acc[t], 0, 0, 0);
        }
    }
    __syncthreads();

    // ---- epilogue: +bias, relu, x dinv(node), pack bf16 -> LDS -> store ----
    int node = nt * 32 + l31;
    float dv = (node < maxr) ? dinv[row0 + node] : 0.0f;
    char* outb = (char*)ldsX;
#pragma unroll
    for (int t = 0; t < 2; ++t) {
        int cb = (mt0 + t) * 32;
#pragma unroll
        for (int q = 0; q < 4; ++q) {
            float v[4];
#pragma unroll
            for (int m = 0; m < 4; ++m) {
                int ch = cb + 8 * q + 4 * half + m;
                float x_ = acc[t][q * 4 + m] + bias[ch];
                x_ = fmaxf(x_, 0.0f);  // relu (both fused layers use it)
                v[m] = x_ * dv;        // pre-scale for next layer's gather
            }
            uint2 pk = make_uint2(f2bf(v[0]) | (f2bf(v[1]) << 16),
                                  f2bf(v[2]) | (f2bf(v[3]) << 16));
            int chunk = (cb >> 3) + q;
            *(uint2*)(outb + node * 256 + ((chunk ^ (node & 7)) * 16) + half * 8) = pk;
        }
    }
    __syncthreads();
    for (int idx = tid; idx < maxr * 16; idx += THREADS) {
        int r = idx >> 4, c = idx & 15;
        out[(size_t)(row0 + r) * 16 + c] = *(uint4*)(outb + r * 256 + ((c ^ (r & 7)) * 16));
    }

    // ---- optional fused P = z2 @ W3 (layer-2 only): z2 tile is in outb -----
    if (outP) {
        floatx16 accp;
#pragma unroll
        for (int q = 0; q < 16; ++q) accp[q] = 0.0f;
        int mt = wv >> 1;  // 0..1 -> 64 out channels
#pragma unroll
        for (int kt = 0; kt < 8; ++kt) {
            int chunk = kt * 2 + half;
            short8 xf = *(const short8*)&ldsX[xrow * 16 + (chunk ^ xsw)];
            int c = mt * 32 + l31;
            short8 wf = *(const short8*)&WtP[c * 16 + chunk];
            accp = __builtin_amdgcn_mfma_f32_32x32x16_bf16(wf, xf, accp, 0, 0, 0);
        }
        __syncthreads();  // all reads of outb (z2) done before overwrite
        int cb = mt * 32;
#pragma unroll
        for (int q = 0; q < 4; ++q) {
            uint2 pk = make_uint2(f2bf(accp[q * 4 + 0]) | (f2bf(accp[q * 4 + 1]) << 16),
                                  f2bf(accp[q * 4 + 2]) | (f2bf(accp[q * 4 + 3]) << 16));
            int chunk = (cb >> 3) + q;
            *(uint2*)(outb + node * 128 + ((chunk ^ (node & 7)) * 16) + half * 8) = pk;
        }
        __syncthreads();
        for (int idx = tid; idx < maxr * 8; idx += THREADS) {
            int r = idx >> 3, c = idx & 7;
            outP[(size_t)(row0 + r) * 8 + c] = *(uint4*)(outb + r * 128 + ((c ^ (r & 7)) * 16));
        }
    }
}

// ---- layer-3 agg fused with mean-pool accumulation -------------------------
__global__ __launch_bounds__(THREADS) void agg_pool(const uint4* __restrict__ Ps,
                                                    const int* __restrict__ row_start,
                                                    const int* __restrict__ esrc,
                                                    const float* __restrict__ dinv,
                                                    const float* __restrict__ bias,
                                                    const int* __restrict__ batch,
                                                    const uint4* __restrict__ zrow,
                                                    float* __restrict__ gsum, int n) {
    __shared__ float gpart[32][65];  // pad 65: lanes hit distinct banks
    __shared__ int used[32];
    int tid = threadIdx.x;
    int lane = tid & 7, grp = tid >> 3;
    int node = blockIdx.x * 32 + grp;
    if (tid < 32) used[tid] = 0;
    for (int idx = tid; idx < 2048; idx += THREADS) gpart[idx >> 6][idx & 63] = 0.0f;
    __syncthreads();
    int gmin = batch[blockIdx.x * 32];  // block's first node is always < n
    const uint4* zl = zrow + lane;
    if (node < n) {
        float ac[8] = {0, 0, 0, 0, 0, 0, 0, 0};
        bf8_acc(Ps[(size_t)node * 8 + lane], ac);  // self
        float dv = dinv[node];
        int s = row_start[node], e = row_start[node + 1];
        int i = s;
        int nmain = (e - s) >> 3;
        if (nmain > 0) {
            int s0 = esrc[i], s1 = esrc[i + 1], s2 = esrc[i + 2], s3 = esrc[i + 3];
            int s4 = esrc[i + 4], s5 = esrc[i + 5], s6 = esrc[i + 6], s7 = esrc[i + 7];
            for (int m = 0; m < nmain; ++m) {
                uint4 v0 = Ps[(size_t)s0 * 8 + lane];
                uint4 v1 = Ps[(size_t)s1 * 8 + lane];
                uint4 v2 = Ps[(size_t)s2 * 8 + lane];
                uint4 v3 = Ps[(size_t)s3 * 8 + lane];
                uint4 v4 = Ps[(size_t)s4 * 8 + lane];
                uint4 v5 = Ps[(size_t)s5 * 8 + lane];
                uint4 v6 = Ps[(size_t)s6 * 8 + lane];
                uint4 v7 = Ps[(size_t)s7 * 8 + lane];
                int ni = i + 8;
                int t0 = esrc[ni], t1 = esrc[ni + 1], t2 = esrc[ni + 2], t3 = esrc[ni + 3];
                int t4 = esrc[ni + 4], t5 = esrc[ni + 5], t6 = esrc[ni + 6], t7 = esrc[ni + 7];
                bf8_acc(v0, ac); bf8_acc(v1, ac); bf8_acc(v2, ac); bf8_acc(v3, ac);
                bf8_acc(v4, ac); bf8_acc(v5, ac); bf8_acc(v6, ac); bf8_acc(v7, ac);
                s0 = t0; s1 = t1; s2 = t2; s3 = t3;
                s4 = t4; s5 = t5; s6 = t6; s7 = t7;
                i = ni;
            }
        }
        if (i < e) {  // masked branchless 8-wide tail
            const uint4* p0 = (i + 0 < e) ? (Ps + ((size_t)esrc[i + 0] * 8 + lane)) : zl;
            const uint4* p1 = (i + 1 < e) ? (Ps + ((size_t)esrc[i + 1] * 8 + lane)) : zl;
            const uint4* p2 = (i + 2 < e) ? (Ps + ((size_t)esrc[i + 2] * 8 + lane)) : zl;
            const uint4* p3 = (i + 3 < e) ? (Ps + ((size_t)esrc[i + 3] * 8 + lane)) : zl;
            const uint4* p4 = (i + 4 < e) ? (Ps + ((size_t)esrc[i + 4] * 8 + lane)) : zl;
            const uint4* p5 = (i + 5 < e) ? (Ps + ((size_t)esrc[i + 5] * 8 + lane)) : zl;
            const uint4* p6 = (i + 6 < e) ? (Ps + ((size_t)esrc[i + 6] * 8 + lane)) : zl;
            const uint4* p7 = (i + 7 < e) ? (Ps + ((size_t)esrc[i + 7] * 8 + lane)) : zl;
            uint4 v0 = *p0; uint4 v1 = *p1; uint4 v2 = *p2; uint4 v3 = *p3;
            uint4 v4 = *p4; uint4 v5 = *p5; uint4 v6 = *p6; uint4 v7 = *p7;
            bf8_acc(v0, ac); bf8_acc(v1, ac); bf8_acc(v2, ac); bf8_acc(v3, ac);
            bf8_acc(v4, ac); bf8_acc(v5, ac); bf8_acc(v6, ac); bf8_acc(v7, ac);
        }
        float4 b0 = ((const float4*)bias)[lane * 2];
        float4 b1 = ((const float4*)bias)[lane * 2 + 1];
        float h[8];
        h[0] = fmaf(dv, ac[0], b0.x); h[1] = fmaf(dv, ac[1], b0.y);
        h[2] = fmaf(dv, ac[2], b0.z); h[3] = fmaf(dv, ac[3], b0.w);
        h[4] = fmaf(dv, ac[4], b1.x); h[5] = fmaf(dv, ac[5], b1.y);
        h[6] = fmaf(dv, ac[6], b1.z); h[7] = fmaf(dv, ac[7], b1.w);
        int g = batch[node];
        int slot = g - gmin;
        if (slot < 32) {
            if (lane == 0) used[slot] = 1;
#pragma unroll
            for (int j = 0; j < 8; ++j) atomicAdd(&gpart[slot][lane * 8 + j], h[j]);
        } else {  // only possible with empty graphs between nodes
#pragma unroll
            for (int j = 0; j < 8; ++j) atomicAdd(&gsum[(size_t)g * 64 + lane * 8 + j], h[j]);
        }
    }
    __syncthreads();
    for (int idx = tid; idx < 2048; idx += THREADS) {
        int s = idx >> 6, ch = idx & 63;
        if (used[s]) atomicAdd(&gsum[(size_t)(gmin + s) * 64 + ch], gpart[s][ch]);
    }
}

// ---- finalize: mean + FC ---------------------------------------------------
__device__ __forceinline__ int dev_lower_bound(const int* a, int n, int key) {
    int lo = 0, hi = n;
    while (lo < hi) {
        int mid = (lo + hi) >> 1;
        if (a[mid] < key) lo = mid + 1;
        else hi = mid;
    }
    return lo;
}

__global__ __launch_bounds__(128) void finalize_fc(const float* __restrict__ gsum,
                                                   const int* __restrict__ batch, int n,
                                                   const float* __restrict__ Wfc,
                                                   const float* __restrict__ bfc,
                                                   float* __restrict__ out) {
    __shared__ float gm[64 * 64];
    __shared__ float cnt[64];
    int t = threadIdx.x;
    if (t < 64)
        cnt[t] = (float)(dev_lower_bound(batch, n, t + 1) - dev_lower_bound(batch, n, t));
    __syncthreads();
    for (int i = t; i < 64 * 64; i += 128) gm[i] = gsum[i] / fmaxf(cnt[i >> 6], 1.0f);
    __syncthreads();
    int g = t >> 1, cls = t & 1;
    float acc = bfc[cls];
    for (int c = 0; c < 64; ++c) acc = fmaf(gm[g * 64 + c], Wfc[c * 2 + cls], acc);
    out[g * 2 + cls] = acc;
}

extern "C" void kernel_launch(void* const* d_in, const int* in_sizes, int n_in,
                              void* d_out, int out_size, void* d_ws, size_t ws_size,
                              hipStream_t stream) {
    const float* x    = (const float*)d_in[0];
    const int*   ei   = (const int*)d_in[1];
    const int*   batch= (const int*)d_in[2];
    const float* W1   = (const float*)d_in[3];
    const float* b1   = (const float*)d_in[4];
    const float* W2   = (const float*)d_in[5];
    const float* b2   = (const float*)d_in[6];
    const float* W3   = (const float*)d_in[7];
    const float* b3   = (const float*)d_in[8];
    const float* Wfc  = (const float*)d_in[9];
    const float* bfc  = (const float*)d_in[10];
    float* out = (float*)d_out;

    const int N = in_sizes[2];        // 100000
    const int E = in_sizes[1] / 2;    // 1600000
    const int* esrc_in = ei;          // edge_index[0]
    const int* edst_in = ei + E;      // edge_index[1]

    // workspace layout (~72 MB)
    uint4* bufA      = (uint4*)d_ws;                  // N*16 uint4 (z, bf16 packed)
    uint4* bufB      = bufA + (size_t)N * 16;         // N*16 uint4
    uint4* bufC      = bufB + (size_t)N * 16;         // N*8 uint4 (Ps)
    int*   esrc      = (int*)(bufC + (size_t)N * 8);  // E
    int*   deg       = esrc + E;                      // N
    int*   cursor    = deg + N;                       // N
    int*   row_start = cursor + N;                    // N+1
    float* dinv      = (float*)(row_start + N + 1);   // N
    float* gsum      = (float*)(dinv + N);            // 64*64
    uint4* Wt1       = (uint4*)(gsum + 64 * 64);      // 2048
    uint4* Wt2       = Wt1 + 2048;                    // 2048
    uint4* Wt3       = Wt2 + 2048;                    // 1024
    float* zrow      = (float*)(Wt3 + 1024);          // 64 floats (zero row)

    // ---- direct CSR build + prep (9 dispatches total) ----
    hipMemsetAsync(deg, 0, (size_t)N * sizeof(int), stream);
    deg_count<<<(E + THREADS * 4 - 1) / (THREADS * 4), THREADS, 0, stream>>>(edst_in, deg, E);
    scan_all<<<1, 1024, 0, stream>>>(deg, row_start, cursor, dinv, gsum, zrow, N, E);
    csr_scatter<<<(E + THREADS * 4 - 1) / (THREADS * 4), THREADS, 0, stream>>>(esrc_in, edst_in,
                                                                               cursor, esrc, E);
    prep_all<<<(N * 16 + 5120 + THREADS - 1) / THREADS, THREADS, 0, stream>>>(
        x, dinv, bufA, W1, W2, W3, Wt1, Wt2, Wt3, N);

    const int GB = (N + 63) / 64;

    // ---- layers (agg-commuted); P = z2@W3 fused into layer 2 ----
    fused_layer<<<GB, THREADS, 0, stream>>>(bufA, Wt1, row_start, esrc, dinv, b1,
                                            (const uint4*)zrow, bufB, nullptr, nullptr, N);
    fused_layer<<<GB, THREADS, 0, stream>>>(bufB, Wt2, row_start, esrc, dinv, b2,
                                            (const uint4*)zrow, bufA, Wt3, bufC, N);
    agg_pool<<<(N + 31) / 32, THREADS, 0, stream>>>(bufC, row_start, esrc, dinv, b3, batch,
                                                    (const uint4*)zrow, gsum, N);

    // ---- finalize ----
    finalize_fc<<<1, 128, 0, stream>>>(gsum, batch, N, Wfc, bfc, out);
}

// Round 7
// 390.029 us; speedup vs baseline: 2.1361x; 2.1361x over previous
//
#include <hip/hip_runtime.h>
#include <hip/hip_bf16.h>

// ---------------------------------------------------------------------------
// GCN via agg-commute: agg(XW) == agg(X)W. z = dinv (.) h stored bf16.
// Fused layer: A_i = dinv_i(sum z[src] + z[i]) -> LDS -> MFMA A@W -> +b, relu,
// x dinv -> bf16. Layer3 P = z2@W3 fused into layer-2 epilogue; agg64 fused
// with mean-pool.
// R16: full revert to R14's build (R15's "direct CSR" lost 416->833us:
//   scan_all was a 309us single-block serial-latency chain at 0.15% occupancy,
//   and global-atomic count/scatter cost ~100us more than the bucketed LDS
//   build). One surgical change kept: agg_pool wave-uniform fast path --
//   batch is sorted, so the 8 nodes of a wave share a graph slot ~98% of the
//   time; detect with __all, reduce channels across groups via 3x shfl_xor,
//   one atomicAdd per channel from group 0 (4x fewer LDS atomics, 8x less
//   same-address contention). Non-uniform waves fall back to the old path.
// ---------------------------------------------------------------------------

#define THREADS 256
#define BSHIFT 9
#define BSIZE 512

typedef __attribute__((ext_vector_type(8))) short short8;
typedef __attribute__((ext_vector_type(16))) float floatx16;

__device__ __forceinline__ unsigned f2bf(float f) {  // fp32 -> bf16 bits, RNE
    unsigned u = __float_as_uint(f);
    return (u + 0x7fffu + ((u >> 16) & 1u)) >> 16;
}

__device__ __forceinline__ void bf8_acc(uint4 v, float* ac) {
    ac[0] += __uint_as_float(v.x << 16);
    ac[1] += __uint_as_float(v.x & 0xffff0000u);
    ac[2] += __uint_as_float(v.y << 16);
    ac[3] += __uint_as_float(v.y & 0xffff0000u);
    ac[4] += __uint_as_float(v.z << 16);
    ac[5] += __uint_as_float(v.z & 0xffff0000u);
    ac[6] += __uint_as_float(v.w << 16);
    ac[7] += __uint_as_float(v.w & 0xffff0000u);
}

// ---- bucketed CSR build ----------------------------------------------------

__global__ __launch_bounds__(THREADS) void bucket_count(const int* __restrict__ dst,
                                                        int* __restrict__ btotal,
                                                        int E, int nbuck) {
    __shared__ int cnt[BSIZE];
    for (int i = threadIdx.x; i < nbuck; i += THREADS) cnt[i] = 0;
    __syncthreads();
    for (int e = blockIdx.x * THREADS + threadIdx.x; e < E; e += gridDim.x * THREADS)
        atomicAdd(&cnt[dst[e] >> BSHIFT], 1);
    __syncthreads();
    for (int i = threadIdx.x; i < nbuck; i += THREADS) {
        int c = cnt[i];
        if (c) atomicAdd(&btotal[i], c);
    }
}

// also zeros gsum + zrow (idle threads, 1-block kernel)
__global__ __launch_bounds__(512) void bucket_scan(const int* __restrict__ btotal,
                                                   int* __restrict__ bbase,
                                                   int* __restrict__ bcursor,
                                                   float* __restrict__ gsum,
                                                   float* __restrict__ zrow,
                                                   int nbuck, int E) {
    __shared__ int lds[512];
    int t = threadIdx.x;
    for (int i = t; i < 64 * 64; i += 512) gsum[i] = 0.0f;
    if (t < 64) zrow[t] = 0.0f;
    int v = (t < nbuck) ? btotal[t] : 0;
    lds[t] = v;
    __syncthreads();
    for (int off = 1; off < 512; off <<= 1) {
        int tv = (t >= off) ? lds[t - off] : 0;
        __syncthreads();
        lds[t] += tv;
        __syncthreads();
    }
    if (t < nbuck) {
        int excl = lds[t] - v;
        bbase[t] = excl;
        bcursor[t] = excl;
    }
    if (t == 0) bbase[nbuck] = E;
}

// chunk = 2048 edges/block; packed pair = (src<<9) | (dst & 511)
__global__ __launch_bounds__(THREADS) void bucket_scatter(const int* __restrict__ src,
                                                          const int* __restrict__ dst,
                                                          int* __restrict__ bcursor,
                                                          int* __restrict__ pairs, int E) {
    __shared__ int cnt[BSIZE];
    __shared__ int base[BSIZE];
    for (int i = threadIdx.x; i < BSIZE; i += THREADS) cnt[i] = 0;
    __syncthreads();
    int e0 = blockIdx.x * 2048;
    int myb[8], myrank[8], mypk[8];
#pragma unroll
    for (int j = 0; j < 8; ++j) {
        int e = e0 + j * THREADS + threadIdx.x;
        myb[j] = -1;
        if (e < E) {
            int d = dst[e];
            mypk[j] = (src[e] << BSHIFT) | (d & (BSIZE - 1));
            myb[j] = d >> BSHIFT;
            myrank[j] = atomicAdd(&cnt[myb[j]], 1);
        }
    }
    __syncthreads();
    for (int i = threadIdx.x; i < BSIZE; i += THREADS) {
        int c = cnt[i];
        base[i] = c ? atomicAdd(&bcursor[i], c) : 0;
    }
    __syncthreads();
#pragma unroll
    for (int j = 0; j < 8; ++j)
        if (myb[j] >= 0) pairs[(size_t)base[myb[j]] + myrank[j]] = mypk[j];
}

// one block per bucket: local count/scan -> row_start+dinv; local cursor -> esrc.
__global__ __launch_bounds__(512) void bucket_fill(const int* __restrict__ pairs,
                                                   const int* __restrict__ bbase,
                                                   int* __restrict__ row_start,
                                                   float* __restrict__ dinv,
                                                   int* __restrict__ esrc,
                                                   int N, int E, int nbuck) {
    __shared__ int cnt[BSIZE];
    __shared__ int scn[BSIZE];
    int b = blockIdx.x, t = threadIdx.x;
    int s = bbase[b], e = bbase[b + 1];
    cnt[t] = 0;
    __syncthreads();
    for (int i = s + t; i < e; i += 512) atomicAdd(&cnt[pairs[i] & (BSIZE - 1)], 1);
    __syncthreads();
    int v = cnt[t];
    scn[t] = v;
    __syncthreads();
    for (int off = 1; off < 512; off <<= 1) {
        int tv = (t >= off) ? scn[t - off] : 0;
        __syncthreads();
        scn[t] += tv;
        __syncthreads();
    }
    int excl = scn[t] - v;
    int g = (b << BSHIFT) + t;
    if (g < N) {
        row_start[g] = s + excl;
        dinv[g] = rsqrtf(1.0f + (float)v);  // deg = 1 + in-degree (self-loop)
    }
    if (b == nbuck - 1 && t == 0) row_start[N] = E;
    scn[t] = excl;  // reuse as cursor
    __syncthreads();
    for (int i = s + t; i < e; i += 512) {
        int p = pairs[i];
        int r = atomicAdd(&scn[p & (BSIZE - 1)], 1);
        esrc[s + r] = ((unsigned)p) >> BSHIFT;
    }
}

// ---- prep: all three W^T (bf16 packed) in one launch -----------------------
__device__ __forceinline__ void wt_pack(const float* W, uint4* Wtp, int C, int li) {
    int c = li >> 4, ch = li & 15;
    unsigned r[8];
#pragma unroll
    for (int j = 0; j < 8; ++j) r[j] = f2bf(W[(size_t)(ch * 8 + j) * C + c]);
    uint4 o;
    o.x = r[0] | (r[1] << 16);
    o.y = r[2] | (r[3] << 16);
    o.z = r[4] | (r[5] << 16);
    o.w = r[6] | (r[7] << 16);
    Wtp[li] = o;
}

__global__ __launch_bounds__(THREADS) void prep_wt_all(const float* __restrict__ W1,
                                                       const float* __restrict__ W2,
                                                       const float* __restrict__ W3,
                                                       uint4* __restrict__ Wt1,
                                                       uint4* __restrict__ Wt2,
                                                       uint4* __restrict__ Wt3) {
    int idx = blockIdx.x * THREADS + threadIdx.x;
    if (idx < 2048) wt_pack(W1, Wt1, 128, idx);
    else if (idx < 4096) wt_pack(W2, Wt2, 128, idx - 2048);
    else if (idx < 5120) wt_pack(W3, Wt3, 64, idx - 4096);
}

// ---- prep: z1 = bf16(dinv (.) x) -------------------------------------------
__global__ __launch_bounds__(THREADS) void prep_x(const float* __restrict__ x,
                                                  const float* __restrict__ dinv,
                                                  uint4* __restrict__ Z, int n) {
    int idx = blockIdx.x * THREADS + threadIdx.x;  // r*16 + chunk
    if (idx >= n * 16) return;
    int r = idx >> 4, c = idx & 15;
    float dv = dinv[r];
    const float* p = x + (size_t)r * 128 + c * 8;
    float4 a = *(const float4*)p;
    float4 b = *(const float4*)(p + 4);
    uint4 o;
    o.x = f2bf(a.x * dv) | (f2bf(a.y * dv) << 16);
    o.y = f2bf(a.z * dv) | (f2bf(a.w * dv) << 16);
    o.z = f2bf(b.x * dv) | (f2bf(b.y * dv) << 16);
    o.w = f2bf(b.z * dv) | (f2bf(b.w * dv) << 16);
    Z[idx] = o;
}

// ---- fused layer: gather -> LDS -> MFMA -> epilogue (+optional P=z2@W3) ----
__global__ __launch_bounds__(THREADS) void fused_layer(const uint4* __restrict__ Z,
                                                       const uint4* __restrict__ Wt,
                                                       const int* __restrict__ row_start,
                                                       const int* __restrict__ esrc,
                                                       const float* __restrict__ dinv,
                                                       const float* __restrict__ bias,
                                                       const uint4* __restrict__ zrow,
                                                       uint4* __restrict__ out,
                                                       const uint4* __restrict__ WtP,
                                                       uint4* __restrict__ outP, int n) {
    __shared__ __align__(16) uint4 ldsX[64 * 16];  // 16KB: A-tile, reused for out-stage
    int row0 = blockIdx.x * 64;
    int maxr = n - row0;
    if (maxr > 64) maxr = 64;
    int tid = threadIdx.x;
    int lane = tid & 15, grp = tid >> 4;
    const uint4* zl = zrow + lane;

    // ---- gather phase: 16 lanes/node, 16 nodes concurrent, 4 rounds ----
    for (int round = 0; round < 4; ++round) {
        int r = round * 16 + grp;
        int node = row0 + r;
        int nd = (node < n) ? node : (n - 1);
        float ac[8] = {0, 0, 0, 0, 0, 0, 0, 0};
        bf8_acc(Z[(size_t)nd * 16 + lane], ac);  // self term z[i]
        float dv = dinv[nd];                     // hoisted: in flight during gather
        int s = row_start[nd], e = row_start[nd + 1];
        int i = s;
        int nmain = (e - s) >> 3;
        if (nmain > 0) {
            int s0 = esrc[i], s1 = esrc[i + 1], s2 = esrc[i + 2], s3 = esrc[i + 3];
            int s4 = esrc[i + 4], s5 = esrc[i + 5], s6 = esrc[i + 6], s7 = esrc[i + 7];
            for (int m = 0; m < nmain; ++m) {
                uint4 v0 = Z[(size_t)s0 * 16 + lane];
                uint4 v1 = Z[(size_t)s1 * 16 + lane];
                uint4 v2 = Z[(size_t)s2 * 16 + lane];
                uint4 v3 = Z[(size_t)s3 * 16 + lane];
                uint4 v4 = Z[(size_t)s4 * 16 + lane];
                uint4 v5 = Z[(size_t)s5 * 16 + lane];
                uint4 v6 = Z[(size_t)s6 * 16 + lane];
                uint4 v7 = Z[(size_t)s7 * 16 + lane];
                int ni = i + 8;
                // prefetch next chunk's esrc (overread <=7 ints: valid ws memory)
                int t0 = esrc[ni], t1 = esrc[ni + 1], t2 = esrc[ni + 2], t3 = esrc[ni + 3];
                int t4 = esrc[ni + 4], t5 = esrc[ni + 5], t6 = esrc[ni + 6], t7 = esrc[ni + 7];
                bf8_acc(v0, ac); bf8_acc(v1, ac); bf8_acc(v2, ac); bf8_acc(v3, ac);
                bf8_acc(v4, ac); bf8_acc(v5, ac); bf8_acc(v6, ac); bf8_acc(v7, ac);
                s0 = t0; s1 = t1; s2 = t2; s3 = t3;
                s4 = t4; s5 = t5; s6 = t6; s7 = t7;
                i = ni;
            }
        }
        if (i < e) {  // masked branchless 8-wide tail (1..7 valid slots)
            const uint4* p0 = (i + 0 < e) ? (Z + ((size_t)esrc[i + 0] * 16 + lane)) : zl;
            const uint4* p1 = (i + 1 < e) ? (Z + ((size_t)esrc[i + 1] * 16 + lane)) : zl;
            const uint4* p2 = (i + 2 < e) ? (Z + ((size_t)esrc[i + 2] * 16 + lane)) : zl;
            const uint4* p3 = (i + 3 < e) ? (Z + ((size_t)esrc[i + 3] * 16 + lane)) : zl;
            const uint4* p4 = (i + 4 < e) ? (Z + ((size_t)esrc[i + 4] * 16 + lane)) : zl;
            const uint4* p5 = (i + 5 < e) ? (Z + ((size_t)esrc[i + 5] * 16 + lane)) : zl;
            const uint4* p6 = (i + 6 < e) ? (Z + ((size_t)esrc[i + 6] * 16 + lane)) : zl;
            const uint4* p7 = (i + 7 < e) ? (Z + ((size_t)esrc[i + 7] * 16 + lane)) : zl;
            uint4 v0 = *p0; uint4 v1 = *p1; uint4 v2 = *p2; uint4 v3 = *p3;
            uint4 v4 = *p4; uint4 v5 = *p5; uint4 v6 = *p6; uint4 v7 = *p7;
            bf8_acc(v0, ac); bf8_acc(v1, ac); bf8_acc(v2, ac); bf8_acc(v3, ac);
            bf8_acc(v4, ac); bf8_acc(v5, ac); bf8_acc(v6, ac); bf8_acc(v7, ac);
        }
        // A_i = dinv_i * (sum z[src] + z[i])
        uint4 o;
        o.x = f2bf(ac[0] * dv) | (f2bf(ac[1] * dv) << 16);
        o.y = f2bf(ac[2] * dv) | (f2bf(ac[3] * dv) << 16);
        o.z = f2bf(ac[4] * dv) | (f2bf(ac[5] * dv) << 16);
        o.w = f2bf(ac[6] * dv) | (f2bf(ac[7] * dv) << 16);
        ldsX[r * 16 + (lane ^ (r & 7))] = o;
    }
    __syncthreads();

    // ---- MFMA phase: D = W^T A^T ; W read from L2-hot global ----
    int l = tid & 63, wv = tid >> 6;
    int l31 = l & 31, half = l >> 5;
    int nt = wv & 1, mt0 = (wv >> 1) * 2;
    floatx16 acc[2];
#pragma unroll
    for (int t = 0; t < 2; ++t)
#pragma unroll
        for (int q = 0; q < 16; ++q) acc[t][q] = 0.0f;
    int xrow = nt * 32 + l31, xsw = xrow & 7;
#pragma unroll
    for (int kt = 0; kt < 8; ++kt) {
        int chunk = kt * 2 + half;
        short8 xf = *(const short8*)&ldsX[xrow * 16 + (chunk ^ xsw)];
#pragma unroll
        for (int t = 0; t < 2; ++t) {
            int c = (mt0 + t) * 32 + l31;
            short8 wf = *(const short8*)&Wt[c * 16 + chunk];
            acc[t] = __builtin_amdgcn_mfma_f32_32x32x16_bf16(wf, xf, acc[t], 0, 0, 0);
        }
    }
    __syncthreads();

    // ---- epilogue: +bias, relu, x dinv(node), pack bf16 -> LDS -> store ----
    int node = nt * 32 + l31;
    float dv = (node < maxr) ? dinv[row0 + node] : 0.0f;
    char* outb = (char*)ldsX;
#pragma unroll
    for (int t = 0; t < 2; ++t) {
        int cb = (mt0 + t) * 32;
#pragma unroll
        for (int q = 0; q < 4; ++q) {
            float v[4];
#pragma unroll
            for (int m = 0; m < 4; ++m) {
                int ch = cb + 8 * q + 4 * half + m;
                float x_ = acc[t][q * 4 + m] + bias[ch];
                x_ = fmaxf(x_, 0.0f);  // relu (both fused layers use it)
                v[m] = x_ * dv;        // pre-scale for next layer's gather
            }
            uint2 pk = make_uint2(f2bf(v[0]) | (f2bf(v[1]) << 16),
                                  f2bf(v[2]) | (f2bf(v[3]) << 16));
            int chunk = (cb >> 3) + q;
            *(uint2*)(outb + node * 256 + ((chunk ^ (node & 7)) * 16) + half * 8) = pk;
        }
    }
    __syncthreads();
    for (int idx = tid; idx < maxr * 16; idx += THREADS) {
        int r = idx >> 4, c = idx & 15;
        out[(size_t)(row0 + r) * 16 + c] = *(uint4*)(outb + r * 256 + ((c ^ (r & 7)) * 16));
    }

    // ---- optional fused P = z2 @ W3 (layer-2 only): z2 tile is in outb -----
    if (outP) {
        floatx16 accp;
#pragma unroll
        for (int q = 0; q < 16; ++q) accp[q] = 0.0f;
        int mt = wv >> 1;  // 0..1 -> 64 out channels
#pragma unroll
        for (int kt = 0; kt < 8; ++kt) {
            int chunk = kt * 2 + half;
            short8 xf = *(const short8*)&ldsX[xrow * 16 + (chunk ^ xsw)];
            int c = mt * 32 + l31;
            short8 wf = *(const short8*)&WtP[c * 16 + chunk];
            accp = __builtin_amdgcn_mfma_f32_32x32x16_bf16(wf, xf, accp, 0, 0, 0);
        }
        __syncthreads();  // all reads of outb (z2) done before overwrite
        int cb = mt * 32;
#pragma unroll
        for (int q = 0; q < 4; ++q) {
            uint2 pk = make_uint2(f2bf(accp[q * 4 + 0]) | (f2bf(accp[q * 4 + 1]) << 16),
                                  f2bf(accp[q * 4 + 2]) | (f2bf(accp[q * 4 + 3]) << 16));
            int chunk = (cb >> 3) + q;
            *(uint2*)(outb + node * 128 + ((chunk ^ (node & 7)) * 16) + half * 8) = pk;
        }
        __syncthreads();
        for (int idx = tid; idx < maxr * 8; idx += THREADS) {
            int r = idx >> 3, c = idx & 7;
            outP[(size_t)(row0 + r) * 8 + c] = *(uint4*)(outb + r * 128 + ((c ^ (r & 7)) * 16));
        }
    }
}

// ---- layer-3 agg fused with mean-pool accumulation -------------------------
// R16: branchless gather (clamped node, h zeroed when invalid) so the whole
// wave stays convergent; wave-uniform slot fast path reduces across the 8
// node-groups via shfl_xor and issues 1 atomicAdd/channel from group 0.
__global__ __launch_bounds__(THREADS) void agg_pool(const uint4* __restrict__ Ps,
                                                    const int* __restrict__ row_start,
                                                    const int* __restrict__ esrc,
                                                    const float* __restrict__ dinv,
                                                    const float* __restrict__ bias,
                                                    const int* __restrict__ batch,
                                                    const uint4* __restrict__ zrow,
                                                    float* __restrict__ gsum, int n) {
    __shared__ float gpart[32][65];  // pad 65: lanes hit distinct banks
    __shared__ int used[32];
    int tid = threadIdx.x;
    int lane = tid & 7, grp = tid >> 3;
    int node = blockIdx.x * 32 + grp;
    bool valid = node < n;
    int nd = valid ? node : (n - 1);
    if (tid < 32) used[tid] = 0;
    for (int idx = tid; idx < 2048; idx += THREADS) gpart[idx >> 6][idx & 63] = 0.0f;
    __syncthreads();
    int gmin = batch[blockIdx.x * 32];  // block's first node is always < n
    const uint4* zl = zrow + lane;

    float ac[8] = {0, 0, 0, 0, 0, 0, 0, 0};
    bf8_acc(Ps[(size_t)nd * 8 + lane], ac);  // self
    float dv = valid ? dinv[nd] : 0.0f;
    int s = row_start[nd], e = row_start[nd + 1];
    int i = s;
    int nmain = (e - s) >> 3;
    if (nmain > 0) {
        int s0 = esrc[i], s1 = esrc[i + 1], s2 = esrc[i + 2], s3 = esrc[i + 3];
        int s4 = esrc[i + 4], s5 = esrc[i + 5], s6 = esrc[i + 6], s7 = esrc[i + 7];
        for (int m = 0; m < nmain; ++m) {
            uint4 v0 = Ps[(size_t)s0 * 8 + lane];
            uint4 v1 = Ps[(size_t)s1 * 8 + lane];
            uint4 v2 = Ps[(size_t)s2 * 8 + lane];
            uint4 v3 = Ps[(size_t)s3 * 8 + lane];
            uint4 v4 = Ps[(size_t)s4 * 8 + lane];
            uint4 v5 = Ps[(size_t)s5 * 8 + lane];
            uint4 v6 = Ps[(size_t)s6 * 8 + lane];
            uint4 v7 = Ps[(size_t)s7 * 8 + lane];
            int ni = i + 8;
            int t0 = esrc[ni], t1 = esrc[ni + 1], t2 = esrc[ni + 2], t3 = esrc[ni + 3];
            int t4 = esrc[ni + 4], t5 = esrc[ni + 5], t6 = esrc[ni + 6], t7 = esrc[ni + 7];
            bf8_acc(v0, ac); bf8_acc(v1, ac); bf8_acc(v2, ac); bf8_acc(v3, ac);
            bf8_acc(v4, ac); bf8_acc(v5, ac); bf8_acc(v6, ac); bf8_acc(v7, ac);
            s0 = t0; s1 = t1; s2 = t2; s3 = t3;
            s4 = t4; s5 = t5; s6 = t6; s7 = t7;
            i = ni;
        }
    }
    if (i < e) {  // masked branchless 8-wide tail
        const uint4* p0 = (i + 0 < e) ? (Ps + ((size_t)esrc[i + 0] * 8 + lane)) : zl;
        const uint4* p1 = (i + 1 < e) ? (Ps + ((size_t)esrc[i + 1] * 8 + lane)) : zl;
        const uint4* p2 = (i + 2 < e) ? (Ps + ((size_t)esrc[i + 2] * 8 + lane)) : zl;
        const uint4* p3 = (i + 3 < e) ? (Ps + ((size_t)esrc[i + 3] * 8 + lane)) : zl;
        const uint4* p4 = (i + 4 < e) ? (Ps + ((size_t)esrc[i + 4] * 8 + lane)) : zl;
        const uint4* p5 = (i + 5 < e) ? (Ps + ((size_t)esrc[i + 5] * 8 + lane)) : zl;
        const uint4* p6 = (i + 6 < e) ? (Ps + ((size_t)esrc[i + 6] * 8 + lane)) : zl;
        const uint4* p7 = (i + 7 < e) ? (Ps + ((size_t)esrc[i + 7] * 8 + lane)) : zl;
        uint4 v0 = *p0; uint4 v1 = *p1; uint4 v2 = *p2; uint4 v3 = *p3;
        uint4 v4 = *p4; uint4 v5 = *p5; uint4 v6 = *p6; uint4 v7 = *p7;
        bf8_acc(v0, ac); bf8_acc(v1, ac); bf8_acc(v2, ac); bf8_acc(v3, ac);
        bf8_acc(v4, ac); bf8_acc(v5, ac); bf8_acc(v6, ac); bf8_acc(v7, ac);
    }
    float4 b0 = ((const float4*)bias)[lane * 2];
    float4 b1 = ((const float4*)bias)[lane * 2 + 1];
    float h[8];
    h[0] = valid ? fmaf(dv, ac[0], b0.x) : 0.0f;
    h[1] = valid ? fmaf(dv, ac[1], b0.y) : 0.0f;
    h[2] = valid ? fmaf(dv, ac[2], b0.z) : 0.0f;
    h[3] = valid ? fmaf(dv, ac[3], b0.w) : 0.0f;
    h[4] = valid ? fmaf(dv, ac[4], b1.x) : 0.0f;
    h[5] = valid ? fmaf(dv, ac[5], b1.y) : 0.0f;
    h[6] = valid ? fmaf(dv, ac[6], b1.z) : 0.0f;
    h[7] = valid ? fmaf(dv, ac[7], b1.w) : 0.0f;
    int g = batch[nd];
    int slot = g - gmin;

    // wave-uniform fast path: 8 nodes of this wave share one slot (~98%)
    int s0w = __shfl(slot, 0, 64);
    bool fast = __all(slot == s0w) && (s0w >= 0) && (s0w < 32);
    if (fast) {
#pragma unroll
        for (int j = 0; j < 8; ++j) {
            float v = h[j];
            v += __shfl_xor(v, 8, 64);
            v += __shfl_xor(v, 16, 64);
            v += __shfl_xor(v, 32, 64);
            h[j] = v;
        }
        if ((tid & 63) < 8) {
            used[s0w] = 1;
#pragma unroll
            for (int j = 0; j < 8; ++j) atomicAdd(&gpart[s0w][lane * 8 + j], h[j]);
        }
    } else if (valid) {
        if (slot >= 0 && slot < 32) {
            if (lane == 0) used[slot] = 1;
#pragma unroll
            for (int j = 0; j < 8; ++j) atomicAdd(&gpart[slot][lane * 8 + j], h[j]);
        } else {  // only possible with empty graphs between nodes
#pragma unroll
            for (int j = 0; j < 8; ++j) atomicAdd(&gsum[(size_t)g * 64 + lane * 8 + j], h[j]);
        }
    }
    __syncthreads();
    for (int idx = tid; idx < 2048; idx += THREADS) {
        int sl = idx >> 6, ch = idx & 63;
        if (used[sl]) atomicAdd(&gsum[(size_t)(gmin + sl) * 64 + ch], gpart[sl][ch]);
    }
}

// ---- finalize: mean + FC ---------------------------------------------------
__device__ __forceinline__ int dev_lower_bound(const int* a, int n, int key) {
    int lo = 0, hi = n;
    while (lo < hi) {
        int mid = (lo + hi) >> 1;
        if (a[mid] < key) lo = mid + 1;
        else hi = mid;
    }
    return lo;
}

__global__ __launch_bounds__(128) void finalize_fc(const float* __restrict__ gsum,
                                                   const int* __restrict__ batch, int n,
                                                   const float* __restrict__ Wfc,
                                                   const float* __restrict__ bfc,
                                                   float* __restrict__ out) {
    __shared__ float gm[64 * 64];
    __shared__ float cnt[64];
    int t = threadIdx.x;
    if (t < 64)
        cnt[t] = (float)(dev_lower_bound(batch, n, t + 1) - dev_lower_bound(batch, n, t));
    __syncthreads();
    for (int i = t; i < 64 * 64; i += 128) gm[i] = gsum[i] / fmaxf(cnt[i >> 6], 1.0f);
    __syncthreads();
    int g = t >> 1, cls = t & 1;
    float acc = bfc[cls];
    for (int c = 0; c < 64; ++c) acc = fmaf(gm[g * 64 + c], Wfc[c * 2 + cls], acc);
    out[g * 2 + cls] = acc;
}

extern "C" void kernel_launch(void* const* d_in, const int* in_sizes, int n_in,
                              void* d_out, int out_size, void* d_ws, size_t ws_size,
                              hipStream_t stream) {
    const float* x    = (const float*)d_in[0];
    const int*   ei   = (const int*)d_in[1];
    const int*   batch= (const int*)d_in[2];
    const float* W1   = (const float*)d_in[3];
    const float* b1   = (const float*)d_in[4];
    const float* W2   = (const float*)d_in[5];
    const float* b2   = (const float*)d_in[6];
    const float* W3   = (const float*)d_in[7];
    const float* b3   = (const float*)d_in[8];
    const float* Wfc  = (const float*)d_in[9];
    const float* bfc  = (const float*)d_in[10];
    float* out = (float*)d_out;

    const int N = in_sizes[2];        // 100000
    const int E = in_sizes[1] / 2;    // 1600000
    const int* esrc_in = ei;          // edge_index[0]
    const int* edst_in = ei + E;      // edge_index[1]
    const int nbuck = (N + BSIZE - 1) >> BSHIFT;  // 196

    // workspace layout (~78 MB)
    uint4* bufA      = (uint4*)d_ws;                  // N*16 uint4 (z, bf16 packed)
    uint4* bufB      = bufA + (size_t)N * 16;         // N*16 uint4
    uint4* bufC      = bufB + (size_t)N * 16;         // N*8 uint4 (Ps)
    int*   pairs     = (int*)(bufC + (size_t)N * 8);  // E (packed src<<9|dst&511)
    int*   esrc      = pairs + E;                     // E
    int*   row_start = esrc + E;                      // N+1
    float* dinv      = (float*)(row_start + N + 1);   // N
    int*   btotal    = (int*)(dinv + N);              // 512
    int*   bbase     = btotal + 512;                  // 513
    int*   bcursor   = bbase + 513;                   // 512
    float* gsum      = (float*)(bcursor + 512);       // 64*64
    uint4* Wt1       = (uint4*)(gsum + 64 * 64);      // 2048
    uint4* Wt2       = Wt1 + 2048;                    // 2048
    uint4* Wt3       = Wt2 + 2048;                    // 1024
    float* zrow      = (float*)(Wt3 + 1024);          // 64 floats (zero row)

    // ---- CSR build + prep (11 dispatches total) ----
    hipMemsetAsync(btotal, 0, 512 * sizeof(int), stream);
    bucket_count<<<512, THREADS, 0, stream>>>(edst_in, btotal, E, nbuck);
    bucket_scan<<<1, 512, 0, stream>>>(btotal, bbase, bcursor, gsum, zrow, nbuck, E);
    bucket_scatter<<<(E + 2047) / 2048, THREADS, 0, stream>>>(esrc_in, edst_in, bcursor, pairs, E);
    bucket_fill<<<nbuck, 512, 0, stream>>>(pairs, bbase, row_start, dinv, esrc, N, E, nbuck);
    prep_wt_all<<<20, THREADS, 0, stream>>>(W1, W2, W3, Wt1, Wt2, Wt3);
    prep_x<<<(N * 16 + THREADS - 1) / THREADS, THREADS, 0, stream>>>(x, dinv, bufA, N);

    const int GB = (N + 63) / 64;

    // ---- layers (agg-commuted); P = z2@W3 fused into layer 2 ----
    fused_layer<<<GB, THREADS, 0, stream>>>(bufA, Wt1, row_start, esrc, dinv, b1,
                                            (const uint4*)zrow, bufB, nullptr, nullptr, N);
    fused_layer<<<GB, THREADS, 0, stream>>>(bufB, Wt2, row_start, esrc, dinv, b2,
                                            (const uint4*)zrow, bufA, Wt3, bufC, N);
    agg_pool<<<(N + 31) / 32, THREADS, 0, stream>>>(bufC, row_start, esrc, dinv, b3, batch,
                                                    (const uint4*)zrow, gsum, N);

    // ---- finalize ----
    finalize_fc<<<1, 128, 0, stream>>>(gsum, batch, N, Wfc, bfc, out);
}

// Round 8
// 373.534 us; speedup vs baseline: 2.2304x; 1.0442x over previous
//
#include <hip/hip_runtime.h>
#include <hip/hip_bf16.h>

// ---------------------------------------------------------------------------
// GCN via agg-commute: agg(XW) == agg(X)W. z = dinv (.) h stored bf16.
// Fused layer: A_i = dinv_i(sum z[src] + z[i]) -> LDS -> MFMA A@W -> +b, relu,
// x dinv -> bf16. Layer3 P = z2@W3 fused into layer-2 epilogue; agg64 fused
// with mean-pool (wave-uniform shfl fast path).
// R17: build-chain tuning (same bucketed algorithm as R14/R16, parameters
//   only -- R15 proved rewrites of this chain are high-risk):
//   (a) bucket_scatter chunk 2048->4096, 16 edges/thread: halves the 400K
//       contested global bcursor atomics, doubles pairs run length to 32B;
//   (b) bucket_fill 512->1024 threads: edge sweeps at 2x TLP (196 blocks
//       were at 19% thread capacity), count/scan stays on first 512 lanes;
//   (c) prep_wt folded into bucket_count's grid (+20 independent blocks).
// ---------------------------------------------------------------------------

#define THREADS 256
#define BSHIFT 9
#define BSIZE 512

typedef __attribute__((ext_vector_type(8))) short short8;
typedef __attribute__((ext_vector_type(16))) float floatx16;

__device__ __forceinline__ unsigned f2bf(float f) {  // fp32 -> bf16 bits, RNE
    unsigned u = __float_as_uint(f);
    return (u + 0x7fffu + ((u >> 16) & 1u)) >> 16;
}

__device__ __forceinline__ void bf8_acc(uint4 v, float* ac) {
    ac[0] += __uint_as_float(v.x << 16);
    ac[1] += __uint_as_float(v.x & 0xffff0000u);
    ac[2] += __uint_as_float(v.y << 16);
    ac[3] += __uint_as_float(v.y & 0xffff0000u);
    ac[4] += __uint_as_float(v.z << 16);
    ac[5] += __uint_as_float(v.z & 0xffff0000u);
    ac[6] += __uint_as_float(v.w << 16);
    ac[7] += __uint_as_float(v.w & 0xffff0000u);
}

// ---- prep: W^T bf16 pack helper --------------------------------------------
__device__ __forceinline__ void wt_pack(const float* W, uint4* Wtp, int C, int li) {
    int c = li >> 4, ch = li & 15;
    unsigned r[8];
#pragma unroll
    for (int j = 0; j < 8; ++j) r[j] = f2bf(W[(size_t)(ch * 8 + j) * C + c]);
    uint4 o;
    o.x = r[0] | (r[1] << 16);
    o.y = r[2] | (r[3] << 16);
    o.z = r[4] | (r[5] << 16);
    o.w = r[6] | (r[7] << 16);
    Wtp[li] = o;
}

// ---- bucketed CSR build ----------------------------------------------------

// blocks [0,512): bucket histogram; blocks [512,532): W^T packing (independent)
__global__ __launch_bounds__(THREADS) void bucket_count(const int* __restrict__ dst,
                                                        int* __restrict__ btotal,
                                                        int E, int nbuck,
                                                        const float* __restrict__ W1,
                                                        const float* __restrict__ W2,
                                                        const float* __restrict__ W3,
                                                        uint4* __restrict__ Wt1,
                                                        uint4* __restrict__ Wt2,
                                                        uint4* __restrict__ Wt3) {
    if (blockIdx.x >= 512) {
        int k = (blockIdx.x - 512) * THREADS + threadIdx.x;
        if (k < 2048) wt_pack(W1, Wt1, 128, k);
        else if (k < 4096) wt_pack(W2, Wt2, 128, k - 2048);
        else if (k < 5120) wt_pack(W3, Wt3, 64, k - 4096);
        return;
    }
    __shared__ int cnt[BSIZE];
    for (int i = threadIdx.x; i < nbuck; i += THREADS) cnt[i] = 0;
    __syncthreads();
    for (int e = blockIdx.x * THREADS + threadIdx.x; e < E; e += 512 * THREADS)
        atomicAdd(&cnt[dst[e] >> BSHIFT], 1);
    __syncthreads();
    for (int i = threadIdx.x; i < nbuck; i += THREADS) {
        int c = cnt[i];
        if (c) atomicAdd(&btotal[i], c);
    }
}

// also zeros gsum + zrow (idle threads, 1-block kernel)
__global__ __launch_bounds__(512) void bucket_scan(const int* __restrict__ btotal,
                                                   int* __restrict__ bbase,
                                                   int* __restrict__ bcursor,
                                                   float* __restrict__ gsum,
                                                   float* __restrict__ zrow,
                                                   int nbuck, int E) {
    __shared__ int lds[512];
    int t = threadIdx.x;
    for (int i = t; i < 64 * 64; i += 512) gsum[i] = 0.0f;
    if (t < 64) zrow[t] = 0.0f;
    int v = (t < nbuck) ? btotal[t] : 0;
    lds[t] = v;
    __syncthreads();
    for (int off = 1; off < 512; off <<= 1) {
        int tv = (t >= off) ? lds[t - off] : 0;
        __syncthreads();
        lds[t] += tv;
        __syncthreads();
    }
    if (t < nbuck) {
        int excl = lds[t] - v;
        bbase[t] = excl;
        bcursor[t] = excl;
    }
    if (t == 0) bbase[nbuck] = E;
}

// chunk = 4096 edges/block (16/thread); packed pair = (src<<9) | (dst & 511)
__global__ __launch_bounds__(THREADS) void bucket_scatter(const int* __restrict__ src,
                                                          const int* __restrict__ dst,
                                                          int* __restrict__ bcursor,
                                                          int* __restrict__ pairs, int E) {
    __shared__ int cnt[BSIZE];
    __shared__ int base[BSIZE];
    for (int i = threadIdx.x; i < BSIZE; i += THREADS) cnt[i] = 0;
    __syncthreads();
    int e0 = blockIdx.x * 4096;
    int myb[16], myrank[16], mypk[16];
#pragma unroll
    for (int j = 0; j < 16; ++j) {
        int e = e0 + j * THREADS + threadIdx.x;
        myb[j] = -1;
        if (e < E) {
            int d = dst[e];
            mypk[j] = (src[e] << BSHIFT) | (d & (BSIZE - 1));
            myb[j] = d >> BSHIFT;
            myrank[j] = atomicAdd(&cnt[myb[j]], 1);
        }
    }
    __syncthreads();
    for (int i = threadIdx.x; i < BSIZE; i += THREADS) {
        int c = cnt[i];
        base[i] = c ? atomicAdd(&bcursor[i], c) : 0;
    }
    __syncthreads();
#pragma unroll
    for (int j = 0; j < 16; ++j)
        if (myb[j] >= 0) pairs[(size_t)base[myb[j]] + myrank[j]] = mypk[j];
}

// one block per bucket, 1024 threads: edge sweeps stride 1024; count/scan on
// first 512 lanes. Local cursor -> esrc (any within-row order is valid).
__global__ __launch_bounds__(1024) void bucket_fill(const int* __restrict__ pairs,
                                                    const int* __restrict__ bbase,
                                                    int* __restrict__ row_start,
                                                    float* __restrict__ dinv,
                                                    int* __restrict__ esrc,
                                                    int N, int E, int nbuck) {
    __shared__ int cnt[BSIZE];
    __shared__ int scn[BSIZE];
    int b = blockIdx.x, t = threadIdx.x;
    int s = bbase[b], e = bbase[b + 1];
    if (t < BSIZE) cnt[t] = 0;
    __syncthreads();
    for (int i = s + t; i < e; i += 1024) atomicAdd(&cnt[pairs[i] & (BSIZE - 1)], 1);
    __syncthreads();
    int v = 0;
    if (t < BSIZE) {
        v = cnt[t];
        scn[t] = v;
    }
    __syncthreads();
    for (int off = 1; off < 512; off <<= 1) {
        int tv = (t >= off && t < BSIZE) ? scn[t - off] : 0;
        __syncthreads();
        if (t < BSIZE) scn[t] += tv;
        __syncthreads();
    }
    if (t < BSIZE) {
        int excl = scn[t] - v;
        int g = (b << BSHIFT) + t;
        if (g < N) {
            row_start[g] = s + excl;
            dinv[g] = rsqrtf(1.0f + (float)v);  // deg = 1 + in-degree (self-loop)
        }
        if (b == nbuck - 1 && t == 0) row_start[N] = E;
        scn[t] = excl;  // reuse as cursor
    }
    __syncthreads();
    for (int i = s + t; i < e; i += 1024) {
        int p = pairs[i];
        int r = atomicAdd(&scn[p & (BSIZE - 1)], 1);
        esrc[s + r] = ((unsigned)p) >> BSHIFT;
    }
}

// ---- prep: z1 = bf16(dinv (.) x) -------------------------------------------
__global__ __launch_bounds__(THREADS) void prep_x(const float* __restrict__ x,
                                                  const float* __restrict__ dinv,
                                                  uint4* __restrict__ Z, int n) {
    int idx = blockIdx.x * THREADS + threadIdx.x;  // r*16 + chunk
    if (idx >= n * 16) return;
    int r = idx >> 4, c = idx & 15;
    float dv = dinv[r];
    const float* p = x + (size_t)r * 128 + c * 8;
    float4 a = *(const float4*)p;
    float4 b = *(const float4*)(p + 4);
    uint4 o;
    o.x = f2bf(a.x * dv) | (f2bf(a.y * dv) << 16);
    o.y = f2bf(a.z * dv) | (f2bf(a.w * dv) << 16);
    o.z = f2bf(b.x * dv) | (f2bf(b.y * dv) << 16);
    o.w = f2bf(b.z * dv) | (f2bf(b.w * dv) << 16);
    Z[idx] = o;
}

// ---- fused layer: gather -> LDS -> MFMA -> epilogue (+optional P=z2@W3) ----
__global__ __launch_bounds__(THREADS) void fused_layer(const uint4* __restrict__ Z,
                                                       const uint4* __restrict__ Wt,
                                                       const int* __restrict__ row_start,
                                                       const int* __restrict__ esrc,
                                                       const float* __restrict__ dinv,
                                                       const float* __restrict__ bias,
                                                       const uint4* __restrict__ zrow,
                                                       uint4* __restrict__ out,
                                                       const uint4* __restrict__ WtP,
                                                       uint4* __restrict__ outP, int n) {
    __shared__ __align__(16) uint4 ldsX[64 * 16];  // 16KB: A-tile, reused for out-stage
    int row0 = blockIdx.x * 64;
    int maxr = n - row0;
    if (maxr > 64) maxr = 64;
    int tid = threadIdx.x;
    int lane = tid & 15, grp = tid >> 4;
    const uint4* zl = zrow + lane;

    // ---- gather phase: 16 lanes/node, 16 nodes concurrent, 4 rounds ----
    for (int round = 0; round < 4; ++round) {
        int r = round * 16 + grp;
        int node = row0 + r;
        int nd = (node < n) ? node : (n - 1);
        float ac[8] = {0, 0, 0, 0, 0, 0, 0, 0};
        bf8_acc(Z[(size_t)nd * 16 + lane], ac);  // self term z[i]
        float dv = dinv[nd];                     // hoisted: in flight during gather
        int s = row_start[nd], e = row_start[nd + 1];
        int i = s;
        int nmain = (e - s) >> 3;
        if (nmain > 0) {
            int s0 = esrc[i], s1 = esrc[i + 1], s2 = esrc[i + 2], s3 = esrc[i + 3];
            int s4 = esrc[i + 4], s5 = esrc[i + 5], s6 = esrc[i + 6], s7 = esrc[i + 7];
            for (int m = 0; m < nmain; ++m) {
                uint4 v0 = Z[(size_t)s0 * 16 + lane];
                uint4 v1 = Z[(size_t)s1 * 16 + lane];
                uint4 v2 = Z[(size_t)s2 * 16 + lane];
                uint4 v3 = Z[(size_t)s3 * 16 + lane];
                uint4 v4 = Z[(size_t)s4 * 16 + lane];
                uint4 v5 = Z[(size_t)s5 * 16 + lane];
                uint4 v6 = Z[(size_t)s6 * 16 + lane];
                uint4 v7 = Z[(size_t)s7 * 16 + lane];
                int ni = i + 8;
                // prefetch next chunk's esrc (overread <=7 ints: valid ws memory)
                int t0 = esrc[ni], t1 = esrc[ni + 1], t2 = esrc[ni + 2], t3 = esrc[ni + 3];
                int t4 = esrc[ni + 4], t5 = esrc[ni + 5], t6 = esrc[ni + 6], t7 = esrc[ni + 7];
                bf8_acc(v0, ac); bf8_acc(v1, ac); bf8_acc(v2, ac); bf8_acc(v3, ac);
                bf8_acc(v4, ac); bf8_acc(v5, ac); bf8_acc(v6, ac); bf8_acc(v7, ac);
                s0 = t0; s1 = t1; s2 = t2; s3 = t3;
                s4 = t4; s5 = t5; s6 = t6; s7 = t7;
                i = ni;
            }
        }
        if (i < e) {  // masked branchless 8-wide tail (1..7 valid slots)
            const uint4* p0 = (i + 0 < e) ? (Z + ((size_t)esrc[i + 0] * 16 + lane)) : zl;
            const uint4* p1 = (i + 1 < e) ? (Z + ((size_t)esrc[i + 1] * 16 + lane)) : zl;
            const uint4* p2 = (i + 2 < e) ? (Z + ((size_t)esrc[i + 2] * 16 + lane)) : zl;
            const uint4* p3 = (i + 3 < e) ? (Z + ((size_t)esrc[i + 3] * 16 + lane)) : zl;
            const uint4* p4 = (i + 4 < e) ? (Z + ((size_t)esrc[i + 4] * 16 + lane)) : zl;
            const uint4* p5 = (i + 5 < e) ? (Z + ((size_t)esrc[i + 5] * 16 + lane)) : zl;
            const uint4* p6 = (i + 6 < e) ? (Z + ((size_t)esrc[i + 6] * 16 + lane)) : zl;
            const uint4* p7 = (i + 7 < e) ? (Z + ((size_t)esrc[i + 7] * 16 + lane)) : zl;
            uint4 v0 = *p0; uint4 v1 = *p1; uint4 v2 = *p2; uint4 v3 = *p3;
            uint4 v4 = *p4; uint4 v5 = *p5; uint4 v6 = *p6; uint4 v7 = *p7;
            bf8_acc(v0, ac); bf8_acc(v1, ac); bf8_acc(v2, ac); bf8_acc(v3, ac);
            bf8_acc(v4, ac); bf8_acc(v5, ac); bf8_acc(v6, ac); bf8_acc(v7, ac);
        }
        // A_i = dinv_i * (sum z[src] + z[i])
        uint4 o;
        o.x = f2bf(ac[0] * dv) | (f2bf(ac[1] * dv) << 16);
        o.y = f2bf(ac[2] * dv) | (f2bf(ac[3] * dv) << 16);
        o.z = f2bf(ac[4] * dv) | (f2bf(ac[5] * dv) << 16);
        o.w = f2bf(ac[6] * dv) | (f2bf(ac[7] * dv) << 16);
        ldsX[r * 16 + (lane ^ (r & 7))] = o;
    }
    __syncthreads();

    // ---- MFMA phase: D = W^T A^T ; W read from L2-hot global ----
    int l = tid & 63, wv = tid >> 6;
    int l31 = l & 31, half = l >> 5;
    int nt = wv & 1, mt0 = (wv >> 1) * 2;
    floatx16 acc[2];
#pragma unroll
    for (int t = 0; t < 2; ++t)
#pragma unroll
        for (int q = 0; q < 16; ++q) acc[t][q] = 0.0f;
    int xrow = nt * 32 + l31, xsw = xrow & 7;
#pragma unroll
    for (int kt = 0; kt < 8; ++kt) {
        int chunk = kt * 2 + half;
        short8 xf = *(const short8*)&ldsX[xrow * 16 + (chunk ^ xsw)];
#pragma unroll
        for (int t = 0; t < 2; ++t) {
            int c = (mt0 + t) * 32 + l31;
            short8 wf = *(const short8*)&Wt[c * 16 + chunk];
            acc[t] = __builtin_amdgcn_mfma_f32_32x32x16_bf16(wf, xf, acc[t], 0, 0, 0);
        }
    }
    __syncthreads();

    // ---- epilogue: +bias, relu, x dinv(node), pack bf16 -> LDS -> store ----
    int node = nt * 32 + l31;
    float dv = (node < maxr) ? dinv[row0 + node] : 0.0f;
    char* outb = (char*)ldsX;
#pragma unroll
    for (int t = 0; t < 2; ++t) {
        int cb = (mt0 + t) * 32;
#pragma unroll
        for (int q = 0; q < 4; ++q) {
            float v[4];
#pragma unroll
            for (int m = 0; m < 4; ++m) {
                int ch = cb + 8 * q + 4 * half + m;
                float x_ = acc[t][q * 4 + m] + bias[ch];
                x_ = fmaxf(x_, 0.0f);  // relu (both fused layers use it)
                v[m] = x_ * dv;        // pre-scale for next layer's gather
            }
            uint2 pk = make_uint2(f2bf(v[0]) | (f2bf(v[1]) << 16),
                                  f2bf(v[2]) | (f2bf(v[3]) << 16));
            int chunk = (cb >> 3) + q;
            *(uint2*)(outb + node * 256 + ((chunk ^ (node & 7)) * 16) + half * 8) = pk;
        }
    }
    __syncthreads();
    for (int idx = tid; idx < maxr * 16; idx += THREADS) {
        int r = idx >> 4, c = idx & 15;
        out[(size_t)(row0 + r) * 16 + c] = *(uint4*)(outb + r * 256 + ((c ^ (r & 7)) * 16));
    }

    // ---- optional fused P = z2 @ W3 (layer-2 only): z2 tile is in outb -----
    if (outP) {
        floatx16 accp;
#pragma unroll
        for (int q = 0; q < 16; ++q) accp[q] = 0.0f;
        int mt = wv >> 1;  // 0..1 -> 64 out channels
#pragma unroll
        for (int kt = 0; kt < 8; ++kt) {
            int chunk = kt * 2 + half;
            short8 xf = *(const short8*)&ldsX[xrow * 16 + (chunk ^ xsw)];
            int c = mt * 32 + l31;
            short8 wf = *(const short8*)&WtP[c * 16 + chunk];
            accp = __builtin_amdgcn_mfma_f32_32x32x16_bf16(wf, xf, accp, 0, 0, 0);
        }
        __syncthreads();  // all reads of outb (z2) done before overwrite
        int cb = mt * 32;
#pragma unroll
        for (int q = 0; q < 4; ++q) {
            uint2 pk = make_uint2(f2bf(accp[q * 4 + 0]) | (f2bf(accp[q * 4 + 1]) << 16),
                                  f2bf(accp[q * 4 + 2]) | (f2bf(accp[q * 4 + 3]) << 16));
            int chunk = (cb >> 3) + q;
            *(uint2*)(outb + node * 128 + ((chunk ^ (node & 7)) * 16) + half * 8) = pk;
        }
        __syncthreads();
        for (int idx = tid; idx < maxr * 8; idx += THREADS) {
            int r = idx >> 3, c = idx & 7;
            outP[(size_t)(row0 + r) * 8 + c] = *(uint4*)(outb + r * 128 + ((c ^ (r & 7)) * 16));
        }
    }
}

// ---- layer-3 agg fused with mean-pool accumulation -------------------------
__global__ __launch_bounds__(THREADS) void agg_pool(const uint4* __restrict__ Ps,
                                                    const int* __restrict__ row_start,
                                                    const int* __restrict__ esrc,
                                                    const float* __restrict__ dinv,
                                                    const float* __restrict__ bias,
                                                    const int* __restrict__ batch,
                                                    const uint4* __restrict__ zrow,
                                                    float* __restrict__ gsum, int n) {
    __shared__ float gpart[32][65];  // pad 65: lanes hit distinct banks
    __shared__ int used[32];
    int tid = threadIdx.x;
    int lane = tid & 7, grp = tid >> 3;
    int node = blockIdx.x * 32 + grp;
    bool valid = node < n;
    int nd = valid ? node : (n - 1);
    if (tid < 32) used[tid] = 0;
    for (int idx = tid; idx < 2048; idx += THREADS) gpart[idx >> 6][idx & 63] = 0.0f;
    __syncthreads();
    int gmin = batch[blockIdx.x * 32];  // block's first node is always < n
    const uint4* zl = zrow + lane;

    float ac[8] = {0, 0, 0, 0, 0, 0, 0, 0};
    bf8_acc(Ps[(size_t)nd * 8 + lane], ac);  // self
    float dv = valid ? dinv[nd] : 0.0f;
    int s = row_start[nd], e = row_start[nd + 1];
    int i = s;
    int nmain = (e - s) >> 3;
    if (nmain > 0) {
        int s0 = esrc[i], s1 = esrc[i + 1], s2 = esrc[i + 2], s3 = esrc[i + 3];
        int s4 = esrc[i + 4], s5 = esrc[i + 5], s6 = esrc[i + 6], s7 = esrc[i + 7];
        for (int m = 0; m < nmain; ++m) {
            uint4 v0 = Ps[(size_t)s0 * 8 + lane];
            uint4 v1 = Ps[(size_t)s1 * 8 + lane];
            uint4 v2 = Ps[(size_t)s2 * 8 + lane];
            uint4 v3 = Ps[(size_t)s3 * 8 + lane];
            uint4 v4 = Ps[(size_t)s4 * 8 + lane];
            uint4 v5 = Ps[(size_t)s5 * 8 + lane];
            uint4 v6 = Ps[(size_t)s6 * 8 + lane];
            uint4 v7 = Ps[(size_t)s7 * 8 + lane];
            int ni = i + 8;
            int t0 = esrc[ni], t1 = esrc[ni + 1], t2 = esrc[ni + 2], t3 = esrc[ni + 3];
            int t4 = esrc[ni + 4], t5 = esrc[ni + 5], t6 = esrc[ni + 6], t7 = esrc[ni + 7];
            bf8_acc(v0, ac); bf8_acc(v1, ac); bf8_acc(v2, ac); bf8_acc(v3, ac);
            bf8_acc(v4, ac); bf8_acc(v5, ac); bf8_acc(v6, ac); bf8_acc(v7, ac);
            s0 = t0; s1 = t1; s2 = t2; s3 = t3;
            s4 = t4; s5 = t5; s6 = t6; s7 = t7;
            i = ni;
        }
    }
    if (i < e) {  // masked branchless 8-wide tail
        const uint4* p0 = (i + 0 < e) ? (Ps + ((size_t)esrc[i + 0] * 8 + lane)) : zl;
        const uint4* p1 = (i + 1 < e) ? (Ps + ((size_t)esrc[i + 1] * 8 + lane)) : zl;
        const uint4* p2 = (i + 2 < e) ? (Ps + ((size_t)esrc[i + 2] * 8 + lane)) : zl;
        const uint4* p3 = (i + 3 < e) ? (Ps + ((size_t)esrc[i + 3] * 8 + lane)) : zl;
        const uint4* p4 = (i + 4 < e) ? (Ps + ((size_t)esrc[i + 4] * 8 + lane)) : zl;
        const uint4* p5 = (i + 5 < e) ? (Ps + ((size_t)esrc[i + 5] * 8 + lane)) : zl;
        const uint4* p6 = (i + 6 < e) ? (Ps + ((size_t)esrc[i + 6] * 8 + lane)) : zl;
        const uint4* p7 = (i + 7 < e) ? (Ps + ((size_t)esrc[i + 7] * 8 + lane)) : zl;
        uint4 v0 = *p0; uint4 v1 = *p1; uint4 v2 = *p2; uint4 v3 = *p3;
        uint4 v4 = *p4; uint4 v5 = *p5; uint4 v6 = *p6; uint4 v7 = *p7;
        bf8_acc(v0, ac); bf8_acc(v1, ac); bf8_acc(v2, ac); bf8_acc(v3, ac);
        bf8_acc(v4, ac); bf8_acc(v5, ac); bf8_acc(v6, ac); bf8_acc(v7, ac);
    }
    float4 b0 = ((const float4*)bias)[lane * 2];
    float4 b1 = ((const float4*)bias)[lane * 2 + 1];
    float h[8];
    h[0] = valid ? fmaf(dv, ac[0], b0.x) : 0.0f;
    h[1] = valid ? fmaf(dv, ac[1], b0.y) : 0.0f;
    h[2] = valid ? fmaf(dv, ac[2], b0.z) : 0.0f;
    h[3] = valid ? fmaf(dv, ac[3], b0.w) : 0.0f;
    h[4] = valid ? fmaf(dv, ac[4], b1.x) : 0.0f;
    h[5] = valid ? fmaf(dv, ac[5], b1.y) : 0.0f;
    h[6] = valid ? fmaf(dv, ac[6], b1.z) : 0.0f;
    h[7] = valid ? fmaf(dv, ac[7], b1.w) : 0.0f;
    int g = batch[nd];
    int slot = g - gmin;

    // wave-uniform fast path: 8 nodes of this wave share one slot (~98%)
    int s0w = __shfl(slot, 0, 64);
    bool fast = __all(slot == s0w) && (s0w >= 0) && (s0w < 32);
    if (fast) {
#pragma unroll
        for (int j = 0; j < 8; ++j) {
            float v = h[j];
            v += __shfl_xor(v, 8, 64);
            v += __shfl_xor(v, 16, 64);
            v += __shfl_xor(v, 32, 64);
            h[j] = v;
        }
        if ((tid & 63) < 8) {
            used[s0w] = 1;
#pragma unroll
            for (int j = 0; j < 8; ++j) atomicAdd(&gpart[s0w][lane * 8 + j], h[j]);
        }
    } else if (valid) {
        if (slot >= 0 && slot < 32) {
            if (lane == 0) used[slot] = 1;
#pragma unroll
            for (int j = 0; j < 8; ++j) atomicAdd(&gpart[slot][lane * 8 + j], h[j]);
        } else {  // only possible with empty graphs between nodes
#pragma unroll
            for (int j = 0; j < 8; ++j) atomicAdd(&gsum[(size_t)g * 64 + lane * 8 + j], h[j]);
        }
    }
    __syncthreads();
    for (int idx = tid; idx < 2048; idx += THREADS) {
        int sl = idx >> 6, ch = idx & 63;
        if (used[sl]) atomicAdd(&gsum[(size_t)(gmin + sl) * 64 + ch], gpart[sl][ch]);
    }
}

// ---- finalize: mean + FC ---------------------------------------------------
__device__ __forceinline__ int dev_lower_bound(const int* a, int n, int key) {
    int lo = 0, hi = n;
    while (lo < hi) {
        int mid = (lo + hi) >> 1;
        if (a[mid] < key) lo = mid + 1;
        else hi = mid;
    }
    return lo;
}

__global__ __launch_bounds__(128) void finalize_fc(const float* __restrict__ gsum,
                                                   const int* __restrict__ batch, int n,
                                                   const float* __restrict__ Wfc,
                                                   const float* __restrict__ bfc,
                                                   float* __restrict__ out) {
    __shared__ float gm[64 * 64];
    __shared__ float cnt[64];
    int t = threadIdx.x;
    if (t < 64)
        cnt[t] = (float)(dev_lower_bound(batch, n, t + 1) - dev_lower_bound(batch, n, t));
    __syncthreads();
    for (int i = t; i < 64 * 64; i += 128) gm[i] = gsum[i] / fmaxf(cnt[i >> 6], 1.0f);
    __syncthreads();
    int g = t >> 1, cls = t & 1;
    float acc = bfc[cls];
    for (int c = 0; c < 64; ++c) acc = fmaf(gm[g * 64 + c], Wfc[c * 2 + cls], acc);
    out[g * 2 + cls] = acc;
}

extern "C" void kernel_launch(void* const* d_in, const int* in_sizes, int n_in,
                              void* d_out, int out_size, void* d_ws, size_t ws_size,
                              hipStream_t stream) {
    const float* x    = (const float*)d_in[0];
    const int*   ei   = (const int*)d_in[1];
    const int*   batch= (const int*)d_in[2];
    const float* W1   = (const float*)d_in[3];
    const float* b1   = (const float*)d_in[4];
    const float* W2   = (const float*)d_in[5];
    const float* b2   = (const float*)d_in[6];
    const float* W3   = (const float*)d_in[7];
    const float* b3   = (const float*)d_in[8];
    const float* Wfc  = (const float*)d_in[9];
    const float* bfc  = (const float*)d_in[10];
    float* out = (float*)d_out;

    const int N = in_sizes[2];        // 100000
    const int E = in_sizes[1] / 2;    // 1600000
    const int* esrc_in = ei;          // edge_index[0]
    const int* edst_in = ei + E;      // edge_index[1]
    const int nbuck = (N + BSIZE - 1) >> BSHIFT;  // 196

    // workspace layout (~78 MB)
    uint4* bufA      = (uint4*)d_ws;                  // N*16 uint4 (z, bf16 packed)
    uint4* bufB      = bufA + (size_t)N * 16;         // N*16 uint4
    uint4* bufC      = bufB + (size_t)N * 16;         // N*8 uint4 (Ps)
    int*   pairs     = (int*)(bufC + (size_t)N * 8);  // E (packed src<<9|dst&511)
    int*   esrc      = pairs + E;                     // E
    int*   row_start = esrc + E;                      // N+1
    float* dinv      = (float*)(row_start + N + 1);   // N
    int*   btotal    = (int*)(dinv + N);              // 512
    int*   bbase     = btotal + 512;                  // 513
    int*   bcursor   = bbase + 513;                   // 512
    float* gsum      = (float*)(bcursor + 512);       // 64*64
    uint4* Wt1       = (uint4*)(gsum + 64 * 64);      // 2048
    uint4* Wt2       = Wt1 + 2048;                    // 2048
    uint4* Wt3       = Wt2 + 2048;                    // 1024
    float* zrow      = (float*)(Wt3 + 1024);          // 64 floats (zero row)

    // ---- CSR build + prep (10 dispatches total) ----
    hipMemsetAsync(btotal, 0, 512 * sizeof(int), stream);
    bucket_count<<<532, THREADS, 0, stream>>>(edst_in, btotal, E, nbuck,
                                              W1, W2, W3, Wt1, Wt2, Wt3);
    bucket_scan<<<1, 512, 0, stream>>>(btotal, bbase, bcursor, gsum, zrow, nbuck, E);
    bucket_scatter<<<(E + 4095) / 4096, THREADS, 0, stream>>>(esrc_in, edst_in, bcursor, pairs, E);
    bucket_fill<<<nbuck, 1024, 0, stream>>>(pairs, bbase, row_start, dinv, esrc, N, E, nbuck);
    prep_x<<<(N * 16 + THREADS - 1) / THREADS, THREADS, 0, stream>>>(x, dinv, bufA, N);

    const int GB = (N + 63) / 64;

    // ---- layers (agg-commuted); P = z2@W3 fused into layer 2 ----
    fused_layer<<<GB, THREADS, 0, stream>>>(bufA, Wt1, row_start, esrc, dinv, b1,
                                            (const uint4*)zrow, bufB, nullptr, nullptr, N);
    fused_layer<<<GB, THREADS, 0, stream>>>(bufB, Wt2, row_start, esrc, dinv, b2,
                                            (const uint4*)zrow, bufA, Wt3, bufC, N);
    agg_pool<<<(N + 31) / 32, THREADS, 0, stream>>>(bufC, row_start, esrc, dinv, b3, batch,
                                                    (const uint4*)zrow, gsum, N);

    // ---- finalize ----
    finalize_fc<<<1, 128, 0, stream>>>(gsum, batch, N, Wfc, bfc, out);
}

// Round 9
// 351.602 us; speedup vs baseline: 2.3696x; 1.0624x over previous
//
#include <hip/hip_runtime.h>
#include <hip/hip_bf16.h>

// ---------------------------------------------------------------------------
// GCN via agg-commute: agg(XW) == agg(X)W. z = dinv (.) h stored bf16.
// Fused layer: A_i = dinv_i(sum z[src] + z[i]) -> LDS -> MFMA A@W -> +b, relu,
// x dinv -> bf16. Layer3 P = z2@W3 fused into layer-2 epilogue; agg64 fused
// with mean-pool (wave-uniform shfl fast path).
// R18: static bucket regions (S=12288 = mean 8192 + 45 sigma: binomial
//   overflow impossible; guarded anyway). Kills bucket_count + bucket_scan
//   entirely (bcursor zero-init doubles as per-bucket count), CSR rows get
//   inter-bucket gaps -> row_end[] replaces row_start[nd+1]. prep_x fused
//   into bucket_fill (dinv already in LDS; x slab contiguous per block).
//   wt_pack rides scatter's grid. bcursor+gsum+zrow = one 18.7KB memset.
//   pairs aliases bufC (disjoint lifetime). 10 -> 7 dispatches.
//   Scatter/fill inner structure unchanged from R17 (measured-good).
// ---------------------------------------------------------------------------

#define THREADS 256
#define BSHIFT 9
#define BSIZE 512
#define SREG 12288  // static slots per bucket region

typedef __attribute__((ext_vector_type(8))) short short8;
typedef __attribute__((ext_vector_type(16))) float floatx16;

__device__ __forceinline__ unsigned f2bf(float f) {  // fp32 -> bf16 bits, RNE
    unsigned u = __float_as_uint(f);
    return (u + 0x7fffu + ((u >> 16) & 1u)) >> 16;
}

__device__ __forceinline__ void bf8_acc(uint4 v, float* ac) {
    ac[0] += __uint_as_float(v.x << 16);
    ac[1] += __uint_as_float(v.x & 0xffff0000u);
    ac[2] += __uint_as_float(v.y << 16);
    ac[3] += __uint_as_float(v.y & 0xffff0000u);
    ac[4] += __uint_as_float(v.z << 16);
    ac[5] += __uint_as_float(v.z & 0xffff0000u);
    ac[6] += __uint_as_float(v.w << 16);
    ac[7] += __uint_as_float(v.w & 0xffff0000u);
}

// ---- prep: W^T bf16 pack helper --------------------------------------------
__device__ __forceinline__ void wt_pack(const float* W, uint4* Wtp, int C, int li) {
    int c = li >> 4, ch = li & 15;
    unsigned r[8];
#pragma unroll
    for (int j = 0; j < 8; ++j) r[j] = f2bf(W[(size_t)(ch * 8 + j) * C + c]);
    uint4 o;
    o.x = r[0] | (r[1] << 16);
    o.y = r[2] | (r[3] << 16);
    o.z = r[4] | (r[5] << 16);
    o.w = r[6] | (r[7] << 16);
    Wtp[li] = o;
}

// ---- bucketed scatter to static regions ------------------------------------
// blocks [0,nscat): scatter; blocks [nscat,nscat+20): W^T packing.
// chunk = 4096 edges/block (16/thread); pair = (src<<9) | (dst & 511).
// bcursor starts at 0; after this kernel bcursor[b] == bucket b's edge count.
__global__ __launch_bounds__(THREADS) void bucket_scatter(const int* __restrict__ src,
                                                          const int* __restrict__ dst,
                                                          int* __restrict__ bcursor,
                                                          int* __restrict__ pairs,
                                                          int E, int nscat,
                                                          const float* __restrict__ W1,
                                                          const float* __restrict__ W2,
                                                          const float* __restrict__ W3,
                                                          uint4* __restrict__ Wt1,
                                                          uint4* __restrict__ Wt2,
                                                          uint4* __restrict__ Wt3) {
    if (blockIdx.x >= nscat) {
        int k = (blockIdx.x - nscat) * THREADS + threadIdx.x;
        if (k < 2048) wt_pack(W1, Wt1, 128, k);
        else if (k < 4096) wt_pack(W2, Wt2, 128, k - 2048);
        else if (k < 5120) wt_pack(W3, Wt3, 64, k - 4096);
        return;
    }
    __shared__ int cnt[BSIZE];
    __shared__ int base[BSIZE];
    for (int i = threadIdx.x; i < BSIZE; i += THREADS) cnt[i] = 0;
    __syncthreads();
    int e0 = blockIdx.x * 4096;
    int myb[16], myrank[16], mypk[16];
#pragma unroll
    for (int j = 0; j < 16; ++j) {
        int e = e0 + j * THREADS + threadIdx.x;
        myb[j] = -1;
        if (e < E) {
            int d = dst[e];
            mypk[j] = (src[e] << BSHIFT) | (d & (BSIZE - 1));
            myb[j] = d >> BSHIFT;
            myrank[j] = atomicAdd(&cnt[myb[j]], 1);
        }
    }
    __syncthreads();
    for (int i = threadIdx.x; i < BSIZE; i += THREADS) {
        int c = cnt[i];
        base[i] = c ? atomicAdd(&bcursor[i], c) : 0;
    }
    __syncthreads();
#pragma unroll
    for (int j = 0; j < 16; ++j)
        if (myb[j] >= 0) {
            int pos = base[myb[j]] + myrank[j];
            if (pos < SREG)  // impossible by binomial tail; guard vs corruption
                pairs[(size_t)myb[j] * SREG + pos] = mypk[j];
        }
}

// one block per bucket, 1024 threads: local histogram/scan -> row_start,
// row_end, dinv, esrc (static region); then fused prep_x for the bucket's
// 512 nodes (z1 = bf16(dinv (.) x); x slab contiguous 256KB).
__global__ __launch_bounds__(1024) void bucket_fill(const int* __restrict__ pairs,
                                                    const int* __restrict__ bcount,
                                                    int* __restrict__ row_start,
                                                    int* __restrict__ row_end,
                                                    float* __restrict__ dinv,
                                                    int* __restrict__ esrc,
                                                    const float* __restrict__ x,
                                                    uint4* __restrict__ Z, int N) {
    __shared__ int cnt[BSIZE];
    __shared__ int scn[BSIZE];
    __shared__ float sdv[BSIZE];
    int b = blockIdx.x, t = threadIdx.x;
    size_t rbase = (size_t)b * SREG;
    int total = bcount[b];
    if (total > SREG) total = SREG;
    if (t < BSIZE) cnt[t] = 0;
    __syncthreads();
    for (int i = t; i < total; i += 1024) atomicAdd(&cnt[pairs[rbase + i] & (BSIZE - 1)], 1);
    __syncthreads();
    int v = 0;
    if (t < BSIZE) {
        v = cnt[t];
        scn[t] = v;
    }
    __syncthreads();
    for (int off = 1; off < 512; off <<= 1) {
        int tv = (t >= off && t < BSIZE) ? scn[t - off] : 0;
        __syncthreads();
        if (t < BSIZE) scn[t] += tv;
        __syncthreads();
    }
    if (t < BSIZE) {
        int excl = scn[t] - v;
        int g = (b << BSHIFT) + t;
        float dv = rsqrtf(1.0f + (float)v);  // deg = 1 + in-degree (self-loop)
        if (g < N) {
            row_start[g] = (int)rbase + excl;
            row_end[g] = (int)rbase + excl + v;
            dinv[g] = dv;
        }
        sdv[t] = dv;
        scn[t] = excl;  // reuse as cursor
    }
    __syncthreads();
    for (int i = t; i < total; i += 1024) {
        int p = pairs[rbase + i];
        int r = atomicAdd(&scn[p & (BSIZE - 1)], 1);
        esrc[rbase + r] = ((unsigned)p) >> BSHIFT;
    }
    // ---- fused prep_x: this bucket's nodes, dinv from LDS ----
    int g0 = b << BSHIFT;
    for (int idx = t; idx < BSIZE * 16; idx += 1024) {
        int rl = idx >> 4;
        int g = g0 + rl;
        if (g >= N) break;  // rl monotonic per thread
        int c = idx & 15;
        float dv = sdv[rl];
        const float* p = x + (size_t)g * 128 + c * 8;
        float4 a = *(const float4*)p;
        float4 bb = *(const float4*)(p + 4);
        uint4 o;
        o.x = f2bf(a.x * dv) | (f2bf(a.y * dv) << 16);
        o.y = f2bf(a.z * dv) | (f2bf(a.w * dv) << 16);
        o.z = f2bf(bb.x * dv) | (f2bf(bb.y * dv) << 16);
        o.w = f2bf(bb.z * dv) | (f2bf(bb.w * dv) << 16);
        Z[(size_t)g * 16 + c] = o;
    }
}

// ---- fused layer: gather -> LDS -> MFMA -> epilogue (+optional P=z2@W3) ----
__global__ __launch_bounds__(THREADS) void fused_layer(const uint4* __restrict__ Z,
                                                       const uint4* __restrict__ Wt,
                                                       const int* __restrict__ row_start,
                                                       const int* __restrict__ row_end,
                                                       const int* __restrict__ esrc,
                                                       const float* __restrict__ dinv,
                                                       const float* __restrict__ bias,
                                                       const uint4* __restrict__ zrow,
                                                       uint4* __restrict__ out,
                                                       const uint4* __restrict__ WtP,
                                                       uint4* __restrict__ outP, int n) {
    __shared__ __align__(16) uint4 ldsX[64 * 16];  // 16KB: A-tile, reused for out-stage
    int row0 = blockIdx.x * 64;
    int maxr = n - row0;
    if (maxr > 64) maxr = 64;
    int tid = threadIdx.x;
    int lane = tid & 15, grp = tid >> 4;
    const uint4* zl = zrow + lane;

    // ---- gather phase: 16 lanes/node, 16 nodes concurrent, 4 rounds ----
    for (int round = 0; round < 4; ++round) {
        int r = round * 16 + grp;
        int node = row0 + r;
        int nd = (node < n) ? node : (n - 1);
        float ac[8] = {0, 0, 0, 0, 0, 0, 0, 0};
        bf8_acc(Z[(size_t)nd * 16 + lane], ac);  // self term z[i]
        float dv = dinv[nd];                     // hoisted: in flight during gather
        int s = row_start[nd], e = row_end[nd];
        int i = s;
        int nmain = (e - s) >> 3;
        if (nmain > 0) {
            int s0 = esrc[i], s1 = esrc[i + 1], s2 = esrc[i + 2], s3 = esrc[i + 3];
            int s4 = esrc[i + 4], s5 = esrc[i + 5], s6 = esrc[i + 6], s7 = esrc[i + 7];
            for (int m = 0; m < nmain; ++m) {
                uint4 v0 = Z[(size_t)s0 * 16 + lane];
                uint4 v1 = Z[(size_t)s1 * 16 + lane];
                uint4 v2 = Z[(size_t)s2 * 16 + lane];
                uint4 v3 = Z[(size_t)s3 * 16 + lane];
                uint4 v4 = Z[(size_t)s4 * 16 + lane];
                uint4 v5 = Z[(size_t)s5 * 16 + lane];
                uint4 v6 = Z[(size_t)s6 * 16 + lane];
                uint4 v7 = Z[(size_t)s7 * 16 + lane];
                int ni = i + 8;
                // prefetch next chunk's esrc (overread <=7 ints: padded region)
                int t0 = esrc[ni], t1 = esrc[ni + 1], t2 = esrc[ni + 2], t3 = esrc[ni + 3];
                int t4 = esrc[ni + 4], t5 = esrc[ni + 5], t6 = esrc[ni + 6], t7 = esrc[ni + 7];
                bf8_acc(v0, ac); bf8_acc(v1, ac); bf8_acc(v2, ac); bf8_acc(v3, ac);
                bf8_acc(v4, ac); bf8_acc(v5, ac); bf8_acc(v6, ac); bf8_acc(v7, ac);
                s0 = t0; s1 = t1; s2 = t2; s3 = t3;
                s4 = t4; s5 = t5; s6 = t6; s7 = t7;
                i = ni;
            }
        }
        if (i < e) {  // masked branchless 8-wide tail (1..7 valid slots)
            const uint4* p0 = (i + 0 < e) ? (Z + ((size_t)esrc[i + 0] * 16 + lane)) : zl;
            const uint4* p1 = (i + 1 < e) ? (Z + ((size_t)esrc[i + 1] * 16 + lane)) : zl;
            const uint4* p2 = (i + 2 < e) ? (Z + ((size_t)esrc[i + 2] * 16 + lane)) : zl;
            const uint4* p3 = (i + 3 < e) ? (Z + ((size_t)esrc[i + 3] * 16 + lane)) : zl;
            const uint4* p4 = (i + 4 < e) ? (Z + ((size_t)esrc[i + 4] * 16 + lane)) : zl;
            const uint4* p5 = (i + 5 < e) ? (Z + ((size_t)esrc[i + 5] * 16 + lane)) : zl;
            const uint4* p6 = (i + 6 < e) ? (Z + ((size_t)esrc[i + 6] * 16 + lane)) : zl;
            const uint4* p7 = (i + 7 < e) ? (Z + ((size_t)esrc[i + 7] * 16 + lane)) : zl;
            uint4 v0 = *p0; uint4 v1 = *p1; uint4 v2 = *p2; uint4 v3 = *p3;
            uint4 v4 = *p4; uint4 v5 = *p5; uint4 v6 = *p6; uint4 v7 = *p7;
            bf8_acc(v0, ac); bf8_acc(v1, ac); bf8_acc(v2, ac); bf8_acc(v3, ac);
            bf8_acc(v4, ac); bf8_acc(v5, ac); bf8_acc(v6, ac); bf8_acc(v7, ac);
        }
        // A_i = dinv_i * (sum z[src] + z[i])
        uint4 o;
        o.x = f2bf(ac[0] * dv) | (f2bf(ac[1] * dv) << 16);
        o.y = f2bf(ac[2] * dv) | (f2bf(ac[3] * dv) << 16);
        o.z = f2bf(ac[4] * dv) | (f2bf(ac[5] * dv) << 16);
        o.w = f2bf(ac[6] * dv) | (f2bf(ac[7] * dv) << 16);
        ldsX[r * 16 + (lane ^ (r & 7))] = o;
    }
    __syncthreads();

    // ---- MFMA phase: D = W^T A^T ; W read from L2-hot global ----
    int l = tid & 63, wv = tid >> 6;
    int l31 = l & 31, half = l >> 5;
    int nt = wv & 1, mt0 = (wv >> 1) * 2;
    floatx16 acc[2];
#pragma unroll
    for (int t = 0; t < 2; ++t)
#pragma unroll
        for (int q = 0; q < 16; ++q) acc[t][q] = 0.0f;
    int xrow = nt * 32 + l31, xsw = xrow & 7;
#pragma unroll
    for (int kt = 0; kt < 8; ++kt) {
        int chunk = kt * 2 + half;
        short8 xf = *(const short8*)&ldsX[xrow * 16 + (chunk ^ xsw)];
#pragma unroll
        for (int t = 0; t < 2; ++t) {
            int c = (mt0 + t) * 32 + l31;
            short8 wf = *(const short8*)&Wt[c * 16 + chunk];
            acc[t] = __builtin_amdgcn_mfma_f32_32x32x16_bf16(wf, xf, acc[t], 0, 0, 0);
        }
    }
    __syncthreads();

    // ---- epilogue: +bias, relu, x dinv(node), pack bf16 -> LDS -> store ----
    int node = nt * 32 + l31;
    float dv = (node < maxr) ? dinv[row0 + node] : 0.0f;
    char* outb = (char*)ldsX;
#pragma unroll
    for (int t = 0; t < 2; ++t) {
        int cb = (mt0 + t) * 32;
#pragma unroll
        for (int q = 0; q < 4; ++q) {
            float v[4];
#pragma unroll
            for (int m = 0; m < 4; ++m) {
                int ch = cb + 8 * q + 4 * half + m;
                float x_ = acc[t][q * 4 + m] + bias[ch];
                x_ = fmaxf(x_, 0.0f);  // relu (both fused layers use it)
                v[m] = x_ * dv;        // pre-scale for next layer's gather
            }
            uint2 pk = make_uint2(f2bf(v[0]) | (f2bf(v[1]) << 16),
                                  f2bf(v[2]) | (f2bf(v[3]) << 16));
            int chunk = (cb >> 3) + q;
            *(uint2*)(outb + node * 256 + ((chunk ^ (node & 7)) * 16) + half * 8) = pk;
        }
    }
    __syncthreads();
    for (int idx = tid; idx < maxr * 16; idx += THREADS) {
        int r = idx >> 4, c = idx & 15;
        out[(size_t)(row0 + r) * 16 + c] = *(uint4*)(outb + r * 256 + ((c ^ (r & 7)) * 16));
    }

    // ---- optional fused P = z2 @ W3 (layer-2 only): z2 tile is in outb -----
    if (outP) {
        floatx16 accp;
#pragma unroll
        for (int q = 0; q < 16; ++q) accp[q] = 0.0f;
        int mt = wv >> 1;  // 0..1 -> 64 out channels
#pragma unroll
        for (int kt = 0; kt < 8; ++kt) {
            int chunk = kt * 2 + half;
            short8 xf = *(const short8*)&ldsX[xrow * 16 + (chunk ^ xsw)];
            int c = mt * 32 + l31;
            short8 wf = *(const short8*)&WtP[c * 16 + chunk];
            accp = __builtin_amdgcn_mfma_f32_32x32x16_bf16(wf, xf, accp, 0, 0, 0);
        }
        __syncthreads();  // all reads of outb (z2) done before overwrite
        int cb = mt * 32;
#pragma unroll
        for (int q = 0; q < 4; ++q) {
            uint2 pk = make_uint2(f2bf(accp[q * 4 + 0]) | (f2bf(accp[q * 4 + 1]) << 16),
                                  f2bf(accp[q * 4 + 2]) | (f2bf(accp[q * 4 + 3]) << 16));
            int chunk = (cb >> 3) + q;
            *(uint2*)(outb + node * 128 + ((chunk ^ (node & 7)) * 16) + half * 8) = pk;
        }
        __syncthreads();
        for (int idx = tid; idx < maxr * 8; idx += THREADS) {
            int r = idx >> 3, c = idx & 7;
            outP[(size_t)(row0 + r) * 8 + c] = *(uint4*)(outb + r * 128 + ((c ^ (r & 7)) * 16));
        }
    }
}

// ---- layer-3 agg fused with mean-pool accumulation -------------------------
__global__ __launch_bounds__(THREADS) void agg_pool(const uint4* __restrict__ Ps,
                                                    const int* __restrict__ row_start,
                                                    const int* __restrict__ row_end,
                                                    const int* __restrict__ esrc,
                                                    const float* __restrict__ dinv,
                                                    const float* __restrict__ bias,
                                                    const int* __restrict__ batch,
                                                    const uint4* __restrict__ zrow,
                                                    float* __restrict__ gsum, int n) {
    __shared__ float gpart[32][65];  // pad 65: lanes hit distinct banks
    __shared__ int used[32];
    int tid = threadIdx.x;
    int lane = tid & 7, grp = tid >> 3;
    int node = blockIdx.x * 32 + grp;
    bool valid = node < n;
    int nd = valid ? node : (n - 1);
    if (tid < 32) used[tid] = 0;
    for (int idx = tid; idx < 2048; idx += THREADS) gpart[idx >> 6][idx & 63] = 0.0f;
    __syncthreads();
    int gmin = batch[blockIdx.x * 32];  // block's first node is always < n
    const uint4* zl = zrow + lane;

    float ac[8] = {0, 0, 0, 0, 0, 0, 0, 0};
    bf8_acc(Ps[(size_t)nd * 8 + lane], ac);  // self
    float dv = valid ? dinv[nd] : 0.0f;
    int s = row_start[nd], e = row_end[nd];
    int i = s;
    int nmain = (e - s) >> 3;
    if (nmain > 0) {
        int s0 = esrc[i], s1 = esrc[i + 1], s2 = esrc[i + 2], s3 = esrc[i + 3];
        int s4 = esrc[i + 4], s5 = esrc[i + 5], s6 = esrc[i + 6], s7 = esrc[i + 7];
        for (int m = 0; m < nmain; ++m) {
            uint4 v0 = Ps[(size_t)s0 * 8 + lane];
            uint4 v1 = Ps[(size_t)s1 * 8 + lane];
            uint4 v2 = Ps[(size_t)s2 * 8 + lane];
            uint4 v3 = Ps[(size_t)s3 * 8 + lane];
            uint4 v4 = Ps[(size_t)s4 * 8 + lane];
            uint4 v5 = Ps[(size_t)s5 * 8 + lane];
            uint4 v6 = Ps[(size_t)s6 * 8 + lane];
            uint4 v7 = Ps[(size_t)s7 * 8 + lane];
            int ni = i + 8;
            int t0 = esrc[ni], t1 = esrc[ni + 1], t2 = esrc[ni + 2], t3 = esrc[ni + 3];
            int t4 = esrc[ni + 4], t5 = esrc[ni + 5], t6 = esrc[ni + 6], t7 = esrc[ni + 7];
            bf8_acc(v0, ac); bf8_acc(v1, ac); bf8_acc(v2, ac); bf8_acc(v3, ac);
            bf8_acc(v4, ac); bf8_acc(v5, ac); bf8_acc(v6, ac); bf8_acc(v7, ac);
            s0 = t0; s1 = t1; s2 = t2; s3 = t3;
            s4 = t4; s5 = t5; s6 = t6; s7 = t7;
            i = ni;
        }
    }
    if (i < e) {  // masked branchless 8-wide tail
        const uint4* p0 = (i + 0 < e) ? (Ps + ((size_t)esrc[i + 0] * 8 + lane)) : zl;
        const uint4* p1 = (i + 1 < e) ? (Ps + ((size_t)esrc[i + 1] * 8 + lane)) : zl;
        const uint4* p2 = (i + 2 < e) ? (Ps + ((size_t)esrc[i + 2] * 8 + lane)) : zl;
        const uint4* p3 = (i + 3 < e) ? (Ps + ((size_t)esrc[i + 3] * 8 + lane)) : zl;
        const uint4* p4 = (i + 4 < e) ? (Ps + ((size_t)esrc[i + 4] * 8 + lane)) : zl;
        const uint4* p5 = (i + 5 < e) ? (Ps + ((size_t)esrc[i + 5] * 8 + lane)) : zl;
        const uint4* p6 = (i + 6 < e) ? (Ps + ((size_t)esrc[i + 6] * 8 + lane)) : zl;
        const uint4* p7 = (i + 7 < e) ? (Ps + ((size_t)esrc[i + 7] * 8 + lane)) : zl;
        uint4 v0 = *p0; uint4 v1 = *p1; uint4 v2 = *p2; uint4 v3 = *p3;
        uint4 v4 = *p4; uint4 v5 = *p5; uint4 v6 = *p6; uint4 v7 = *p7;
        bf8_acc(v0, ac); bf8_acc(v1, ac); bf8_acc(v2, ac); bf8_acc(v3, ac);
        bf8_acc(v4, ac); bf8_acc(v5, ac); bf8_acc(v6, ac); bf8_acc(v7, ac);
    }
    float4 b0 = ((const float4*)bias)[lane * 2];
    float4 b1 = ((const float4*)bias)[lane * 2 + 1];
    float h[8];
    h[0] = valid ? fmaf(dv, ac[0], b0.x) : 0.0f;
    h[1] = valid ? fmaf(dv, ac[1], b0.y) : 0.0f;
    h[2] = valid ? fmaf(dv, ac[2], b0.z) : 0.0f;
    h[3] = valid ? fmaf(dv, ac[3], b0.w) : 0.0f;
    h[4] = valid ? fmaf(dv, ac[4], b1.x) : 0.0f;
    h[5] = valid ? fmaf(dv, ac[5], b1.y) : 0.0f;
    h[6] = valid ? fmaf(dv, ac[6], b1.z) : 0.0f;
    h[7] = valid ? fmaf(dv, ac[7], b1.w) : 0.0f;
    int g = batch[nd];
    int slot = g - gmin;

    // wave-uniform fast path: 8 nodes of this wave share one slot (~98%)
    int s0w = __shfl(slot, 0, 64);
    bool fast = __all(slot == s0w) && (s0w >= 0) && (s0w < 32);
    if (fast) {
#pragma unroll
        for (int j = 0; j < 8; ++j) {
            float v = h[j];
            v += __shfl_xor(v, 8, 64);
            v += __shfl_xor(v, 16, 64);
            v += __shfl_xor(v, 32, 64);
            h[j] = v;
        }
        if ((tid & 63) < 8) {
            used[s0w] = 1;
#pragma unroll
            for (int j = 0; j < 8; ++j) atomicAdd(&gpart[s0w][lane * 8 + j], h[j]);
        }
    } else if (valid) {
        if (slot >= 0 && slot < 32) {
            if (lane == 0) used[slot] = 1;
#pragma unroll
            for (int j = 0; j < 8; ++j) atomicAdd(&gpart[slot][lane * 8 + j], h[j]);
        } else {  // only possible with empty graphs between nodes
#pragma unroll
            for (int j = 0; j < 8; ++j) atomicAdd(&gsum[(size_t)g * 64 + lane * 8 + j], h[j]);
        }
    }
    __syncthreads();
    for (int idx = tid; idx < 2048; idx += THREADS) {
        int sl = idx >> 6, ch = idx & 63;
        if (used[sl]) atomicAdd(&gsum[(size_t)(gmin + sl) * 64 + ch], gpart[sl][ch]);
    }
}

// ---- finalize: mean + FC ---------------------------------------------------
__device__ __forceinline__ int dev_lower_bound(const int* a, int n, int key) {
    int lo = 0, hi = n;
    while (lo < hi) {
        int mid = (lo + hi) >> 1;
        if (a[mid] < key) lo = mid + 1;
        else hi = mid;
    }
    return lo;
}

__global__ __launch_bounds__(128) void finalize_fc(const float* __restrict__ gsum,
                                                   const int* __restrict__ batch, int n,
                                                   const float* __restrict__ Wfc,
                                                   const float* __restrict__ bfc,
                                                   float* __restrict__ out) {
    __shared__ float gm[64 * 64];
    __shared__ float cnt[64];
    int t = threadIdx.x;
    if (t < 64)
        cnt[t] = (float)(dev_lower_bound(batch, n, t + 1) - dev_lower_bound(batch, n, t));
    __syncthreads();
    for (int i = t; i < 64 * 64; i += 128) gm[i] = gsum[i] / fmaxf(cnt[i >> 6], 1.0f);
    __syncthreads();
    int g = t >> 1, cls = t & 1;
    float acc = bfc[cls];
    for (int c = 0; c < 64; ++c) acc = fmaf(gm[g * 64 + c], Wfc[c * 2 + cls], acc);
    out[g * 2 + cls] = acc;
}

extern "C" void kernel_launch(void* const* d_in, const int* in_sizes, int n_in,
                              void* d_out, int out_size, void* d_ws, size_t ws_size,
                              hipStream_t stream) {
    const float* x    = (const float*)d_in[0];
    const int*   ei   = (const int*)d_in[1];
    const int*   batch= (const int*)d_in[2];
    const float* W1   = (const float*)d_in[3];
    const float* b1   = (const float*)d_in[4];
    const float* W2   = (const float*)d_in[5];
    const float* b2   = (const float*)d_in[6];
    const float* W3   = (const float*)d_in[7];
    const float* b3   = (const float*)d_in[8];
    const float* Wfc  = (const float*)d_in[9];
    const float* bfc  = (const float*)d_in[10];
    float* out = (float*)d_out;

    const int N = in_sizes[2];        // 100000
    const int E = in_sizes[1] / 2;    // 1600000
    const int* esrc_in = ei;          // edge_index[0]
    const int* edst_in = ei + E;      // edge_index[1]
    const int nbuck = (N + BSIZE - 1) >> BSHIFT;  // 196
    const int nscat = (E + 4095) / 4096;          // 391

    // workspace layout (~75 MB); pairs aliases bufC (disjoint lifetimes)
    uint4* bufA      = (uint4*)d_ws;                  // N*16 uint4 (z, bf16 packed)
    uint4* bufB      = bufA + (size_t)N * 16;         // N*16 uint4
    uint4* bufC      = bufB + (size_t)N * 16;         // N*8 uint4 (Ps)
    int*   pairs     = (int*)bufC;                    // nbuck*SREG ints (<= bufC)
    int*   esrc      = (int*)(bufC + (size_t)N * 8);  // nbuck*SREG + 8 ints
    int*   row_start = esrc + (size_t)nbuck * SREG + 8;  // N
    int*   row_end   = row_start + N;                 // N
    float* dinv      = (float*)(row_end + N);         // N
    int*   bcursor   = (int*)(dinv + N);              // 512  ┐
    float* gsum      = (float*)(bcursor + 512);       // 4096 ├ one memset region
    float* zrow      = gsum + 64 * 64;                // 64   ┘
    uint4* Wt1       = (uint4*)(zrow + 64);           // 2048
    uint4* Wt2       = Wt1 + 2048;                    // 2048
    uint4* Wt3       = Wt2 + 2048;                    // 1024

    // ---- build + prep (7 dispatches total) ----
    hipMemsetAsync(bcursor, 0, (512 + 64 * 64 + 64) * sizeof(int), stream);
    bucket_scatter<<<nscat + 20, THREADS, 0, stream>>>(esrc_in, edst_in, bcursor, pairs, E,
                                                       nscat, W1, W2, W3, Wt1, Wt2, Wt3);
    bucket_fill<<<nbuck, 1024, 0, stream>>>(pairs, bcursor, row_start, row_end, dinv, esrc,
                                            x, bufA, N);

    const int GB = (N + 63) / 64;

    // ---- layers (agg-commuted); P = z2@W3 fused into layer 2 ----
    fused_layer<<<GB, THREADS, 0, stream>>>(bufA, Wt1, row_start, row_end, esrc, dinv, b1,
                                            (const uint4*)zrow, bufB, nullptr, nullptr, N);
    fused_layer<<<GB, THREADS, 0, stream>>>(bufB, Wt2, row_start, row_end, esrc, dinv, b2,
                                            (const uint4*)zrow, bufA, Wt3, bufC, N);
    agg_pool<<<(N + 31) / 32, THREADS, 0, stream>>>(bufC, row_start, row_end, esrc, dinv, b3,
                                                    batch, (const uint4*)zrow, gsum, N);

    // ---- finalize ----
    finalize_fc<<<1, 128, 0, stream>>>(gsum, batch, N, Wfc, bfc, out);
}